// Round 1
// baseline (5880.459 us; speedup 1.0000x reference)
//
#include <hip/hip_runtime.h>
#include <math.h>

#define H 128
#define H2 256

__device__ __forceinline__ float gelu_f(float x) {
  return 0.5f * x * (1.0f + erff(x * 0.70710678118654752440f));
}

// ---------------- elementwise / small kernels ----------------

__global__ __launch_bounds__(256) void fill1_kernel(float* p, int n) {
  int i = blockIdx.x * 256 + threadIdx.x;
  if (i < n) p[i] = 1.0f;
}

__global__ __launch_bounds__(256) void deg_count_kernel(float* deg, const int* __restrict__ dst, int E) {
  int i = blockIdx.x * 256 + threadIdx.x;
  if (i < E) atomicAdd(&deg[dst[i]], 1.0f);
}

__global__ __launch_bounds__(256) void rsqrt_kernel(float* p, int n) {
  int i = blockIdx.x * 256 + threadIdx.x;
  if (i < n) p[i] = rsqrtf(fmaxf(p[i], 1.0f));
}

__global__ __launch_bounds__(256) void count_kernel(float* counts, const int* __restrict__ batch, int n) {
  int i = blockIdx.x * 256 + threadIdx.x;
  if (i < n) atomicAdd(&counts[batch[i]], 1.0f);
}

__global__ __launch_bounds__(256) void vn_init_kernel(float* vn, const float* __restrict__ emb, int n) {
  int i = blockIdx.x * 256 + threadIdx.x;
  if (i < n) vn[i] = emb[i & (H - 1)];
}

__global__ __launch_bounds__(256) void add_vn_kernel(float* __restrict__ x, const float* __restrict__ vn,
                                                     const int* __restrict__ batch, int NH) {
  int i = blockIdx.x * 256 + threadIdx.x;
  if (i < NH) x[i] += vn[batch[i >> 7] * H + (i & (H - 1))];
}

__global__ __launch_bounds__(256) void selfloop_kernel(float* __restrict__ agg, const float* __restrict__ h,
                                                       const float* __restrict__ dinv, int NH) {
  int i = blockIdx.x * 256 + threadIdx.x;
  if (i < NH) { float d = dinv[i >> 7]; agg[i] = h[i] * d * d; }
}

__global__ __launch_bounds__(256) void scatter_kernel(const float* __restrict__ h, const int* __restrict__ src,
                                                      const int* __restrict__ dst, const float* __restrict__ dinv,
                                                      float* __restrict__ agg, int E) {
  int i = blockIdx.x * 256 + threadIdx.x;
  int e = i >> 7;
  if (e < E) {
    int c = i & (H - 1);
    int s = src[e], d = dst[e];
    atomicAdd(&agg[d * H + c], h[s * H + c] * dinv[s] * dinv[d]);
  }
}

__global__ __launch_bounds__(256) void combine_kernel(float* __restrict__ x, const float* __restrict__ agg,
                                                      const float* __restrict__ bias, int NH) {
  int i = blockIdx.x * 256 + threadIdx.x;
  if (i < NH) x[i] += agg[i] + bias[i & (H - 1)];
}

__global__ __launch_bounds__(256) void bn_reduce_kernel(const float* __restrict__ x, float* __restrict__ stats, int N) {
  __shared__ float ls[256], ls2[256];
  int t = threadIdx.x;
  int c = t & (H - 1);
  int r0 = blockIdx.x * 128 + (t >> 7);
  float s = 0.f, s2 = 0.f;
  for (int k = 0; k < 64; k++) {
    int r = r0 + k * 2;
    if (r < N) { float v = x[r * H + c]; s += v; s2 += v * v; }
  }
  ls[t] = s; ls2[t] = s2;
  __syncthreads();
  if (t < 128) {
    atomicAdd(&stats[c], ls[t] + ls[t + 128]);
    atomicAdd(&stats[H + c], ls2[t] + ls2[t + 128]);
  }
}

__global__ __launch_bounds__(128) void bn_finalize_kernel(const float* __restrict__ stats, const float* __restrict__ g,
                                                          const float* __restrict__ b, float* __restrict__ scsh,
                                                          float invN) {
  int c = threadIdx.x;  // 128 threads
  float m = stats[c] * invN;
  float v = stats[H + c] * invN - m * m;
  float sc = rsqrtf(v + 1e-5f) * g[c];
  scsh[c] = sc;
  scsh[H + c] = b[c] - m * sc;
}

__global__ __launch_bounds__(256) void bn_apply_kernel(float* __restrict__ x, const float* __restrict__ scsh, int NH) {
  int i = blockIdx.x * 256 + threadIdx.x;
  if (i < NH) { int c = i & (H - 1); x[i] = x[i] * scsh[c] + scsh[H + c]; }
}

__global__ __launch_bounds__(256) void pool_kernel(float* __restrict__ pooled, const float* __restrict__ x,
                                                   const int* __restrict__ batch, int NH) {
  int i = blockIdx.x * 256 + threadIdx.x;
  if (i < NH) atomicAdd(&pooled[batch[i >> 7] * H + (i & (H - 1))], x[i]);
}

// ---------------- tiled fp32 GEMM ----------------
// C[M x Ncol] = epilogue(A[M x K] @ B[K x Ncol] + bias), epilogue: optional GELU, optional (+= old C)
// 64x64 tile, 256 threads, 4x4 micro-tile. As stored transposed [16][64] so fragment reads are b128.
template <int ACT, int RES, int HASBIAS>
__global__ __launch_bounds__(256) void gemm_kernel(const float* __restrict__ A, const float* __restrict__ B,
                                                   const float* __restrict__ bias, float* __restrict__ C,
                                                   int M, int K, int Ncol) {
  __shared__ float As[16 * 64];
  __shared__ float Bs[16 * 64];
  int tid = threadIdx.x;
  int tx = tid & 15, ty = tid >> 4;
  int row0 = blockIdx.x * 64;
  int col0 = blockIdx.y * 64;

  float acc[4][4] = {};

  int aq = tid * 4;
  int ar = aq >> 4, ac = aq & 15;   // A-tile row (0..63), k-col (0,4,8,12)
  int bq = tid * 4;
  int br = bq >> 6, bc = bq & 63;   // B-tile k-row (0..15), col (0..60 step 4)

  for (int k0 = 0; k0 < K; k0 += 16) {
    int gr = row0 + ar;
    float4 av;
    if (gr < M) av = *(const float4*)&A[gr * K + k0 + ac];
    else av = make_float4(0.f, 0.f, 0.f, 0.f);
    As[(ac + 0) * 64 + ar] = av.x;
    As[(ac + 1) * 64 + ar] = av.y;
    As[(ac + 2) * 64 + ar] = av.z;
    As[(ac + 3) * 64 + ar] = av.w;
    float4 bv = *(const float4*)&B[(k0 + br) * Ncol + col0 + bc];
    *(float4*)&Bs[bq] = bv;
    __syncthreads();
#pragma unroll
    for (int kk = 0; kk < 16; kk++) {
      float4 a4 = *(const float4*)&As[kk * 64 + ty * 4];
      float4 b4 = *(const float4*)&Bs[kk * 64 + tx * 4];
      float a[4] = {a4.x, a4.y, a4.z, a4.w};
      float b[4] = {b4.x, b4.y, b4.z, b4.w};
#pragma unroll
      for (int i = 0; i < 4; i++)
#pragma unroll
        for (int j = 0; j < 4; j++) acc[i][j] += a[i] * b[j];
    }
    __syncthreads();
  }

  int c0 = col0 + tx * 4;
  float4 bf = make_float4(0.f, 0.f, 0.f, 0.f);
  if (HASBIAS) bf = *(const float4*)&bias[c0];
#pragma unroll
  for (int i = 0; i < 4; i++) {
    int r = row0 + ty * 4 + i;
    if (r < M) {
      float v0 = acc[i][0] + bf.x;
      float v1 = acc[i][1] + bf.y;
      float v2 = acc[i][2] + bf.z;
      float v3 = acc[i][3] + bf.w;
      if (ACT) { v0 = gelu_f(v0); v1 = gelu_f(v1); v2 = gelu_f(v2); v3 = gelu_f(v3); }
      float* p = &C[r * Ncol + c0];
      if (RES) {
        float4 old = *(const float4*)p;
        v0 += old.x; v1 += old.y; v2 += old.z; v3 += old.w;
      }
      *(float4*)p = make_float4(v0, v1, v2, v3);
    }
  }
}

// ---------------- single-block 64-row MLPs ----------------
// vn = gelu(bn(gelu(bn((vn + pooled*inv) @ W1 + b1)) @ W2 + b2))
__global__ __launch_bounds__(256) void vn_mlp_kernel(float* __restrict__ vn, const float* __restrict__ pooled,
                                                     const float* __restrict__ counts,
                                                     const float* __restrict__ W1, const float* __restrict__ b1,
                                                     const float* __restrict__ g1, const float* __restrict__ be1,
                                                     const float* __restrict__ W2, const float* __restrict__ b2,
                                                     const float* __restrict__ g2, const float* __restrict__ be2) {
  __shared__ float sh[64 * 256];  // 64 KB: first 32KB = updated vn (64x128), then reused as h1 (64x256)
  int t = threadIdx.x;
  for (int idx = t; idx < 64 * H; idx += 256) {
    int g = idx >> 7;
    sh[idx] = vn[idx] + pooled[idx] / fmaxf(counts[g], 1.0f);
  }
  __syncthreads();

  // h1 column t for all 64 graphs, kept in registers
  float col[64];
  float bj = b1[t];
#pragma unroll
  for (int g = 0; g < 64; g++) col[g] = bj;
  for (int k0 = 0; k0 < H; k0 += 4) {
    float w0 = W1[(k0 + 0) * H2 + t];
    float w1 = W1[(k0 + 1) * H2 + t];
    float w2 = W1[(k0 + 2) * H2 + t];
    float w3 = W1[(k0 + 3) * H2 + t];
#pragma unroll
    for (int g = 0; g < 64; g++) {
      float4 v = *(const float4*)&sh[g * H + k0];
      col[g] += v.x * w0 + v.y * w1 + v.z * w2 + v.w * w3;
    }
  }
  // BN over 64 rows + gelu (register-local: thread owns the whole column)
  {
    float s = 0.f, s2 = 0.f;
#pragma unroll
    for (int g = 0; g < 64; g++) { s += col[g]; s2 += col[g] * col[g]; }
    float m = s * (1.f / 64.f);
    float var = s2 * (1.f / 64.f) - m * m;
    float sc = rsqrtf(var + 1e-5f) * g1[t];
    float shf = be1[t];
#pragma unroll
    for (int g = 0; g < 64; g++) col[g] = gelu_f((col[g] - m) * sc + shf);
  }
  __syncthreads();  // done reading the vn staging region
#pragma unroll
  for (int g = 0; g < 64; g++) sh[g * H2 + t] = col[g];
  __syncthreads();

  if (t < H) {
    float c2[64];
    float bj2 = b2[t];
#pragma unroll
    for (int g = 0; g < 64; g++) c2[g] = bj2;
    for (int k0 = 0; k0 < H2; k0 += 4) {
      float w0 = W2[(k0 + 0) * H + t];
      float w1 = W2[(k0 + 1) * H + t];
      float w2 = W2[(k0 + 2) * H + t];
      float w3 = W2[(k0 + 3) * H + t];
#pragma unroll
      for (int g = 0; g < 64; g++) {
        float4 v = *(const float4*)&sh[g * H2 + k0];
        c2[g] += v.x * w0 + v.y * w1 + v.z * w2 + v.w * w3;
      }
    }
    float s = 0.f, s2 = 0.f;
#pragma unroll
    for (int g = 0; g < 64; g++) { s += c2[g]; s2 += c2[g] * c2[g]; }
    float m = s * (1.f / 64.f);
    float var = s2 * (1.f / 64.f) - m * m;
    float sc = rsqrtf(var + 1e-5f) * g2[t];
    float shf = be2[t];
#pragma unroll
    for (int g = 0; g < 64; g++) vn[g * H + t] = gelu_f((c2[g] - m) * sc + shf);
  }
}

// out = gelu(gelu(pooled @ W1 + b1) @ W2 + b2)
__global__ __launch_bounds__(256) void post_kernel(float* __restrict__ out, const float* __restrict__ pooled,
                                                   const float* __restrict__ W1, const float* __restrict__ b1,
                                                   const float* __restrict__ W2, const float* __restrict__ b2) {
  __shared__ float sh[64 * 256];
  int t = threadIdx.x;
  for (int idx = t; idx < 64 * H; idx += 256) sh[idx] = pooled[idx];
  __syncthreads();

  float col[64];
  float bj = b1[t];
#pragma unroll
  for (int g = 0; g < 64; g++) col[g] = bj;
  for (int k0 = 0; k0 < H; k0 += 4) {
    float w0 = W1[(k0 + 0) * H2 + t];
    float w1 = W1[(k0 + 1) * H2 + t];
    float w2 = W1[(k0 + 2) * H2 + t];
    float w3 = W1[(k0 + 3) * H2 + t];
#pragma unroll
    for (int g = 0; g < 64; g++) {
      float4 v = *(const float4*)&sh[g * H + k0];
      col[g] += v.x * w0 + v.y * w1 + v.z * w2 + v.w * w3;
    }
  }
#pragma unroll
  for (int g = 0; g < 64; g++) col[g] = gelu_f(col[g]);
  __syncthreads();
#pragma unroll
  for (int g = 0; g < 64; g++) sh[g * H2 + t] = col[g];
  __syncthreads();

  if (t < H) {
    float c2[64];
    float bj2 = b2[t];
#pragma unroll
    for (int g = 0; g < 64; g++) c2[g] = bj2;
    for (int k0 = 0; k0 < H2; k0 += 4) {
      float w0 = W2[(k0 + 0) * H + t];
      float w1 = W2[(k0 + 1) * H + t];
      float w2 = W2[(k0 + 2) * H + t];
      float w3 = W2[(k0 + 3) * H + t];
#pragma unroll
      for (int g = 0; g < 64; g++) {
        float4 v = *(const float4*)&sh[g * H2 + k0];
        c2[g] += v.x * w0 + v.y * w1 + v.z * w2 + v.w * w3;
      }
    }
#pragma unroll
    for (int g = 0; g < 64; g++) out[g * H + t] = gelu_f(c2[g]);
  }
}

// ---------------- host launch ----------------

extern "C" void kernel_launch(void* const* d_in, const int* in_sizes, int n_in,
                              void* d_out, int out_size, void* d_ws, size_t ws_size,
                              hipStream_t stream) {
  const float* x_in   = (const float*)d_in[0];
  const int*   edge   = (const int*)d_in[1];
  const int*   batch  = (const int*)d_in[2];
  const float* pre_W1 = (const float*)d_in[3];
  const float* pre_b1 = (const float*)d_in[4];
  const float* pre_W2 = (const float*)d_in[5];
  const float* pre_b2 = (const float*)d_in[6];
  const float* conv_W = (const float*)d_in[7];
  const float* conv_b = (const float*)d_in[8];
  const float* bn_g   = (const float*)d_in[9];
  const float* bn_b   = (const float*)d_in[10];
  const float* ffn_W1 = (const float*)d_in[11];
  const float* ffn_b1 = (const float*)d_in[12];
  const float* ffn_W2 = (const float*)d_in[13];
  const float* ffn_b2 = (const float*)d_in[14];
  const float* vn_W1  = (const float*)d_in[15];
  const float* vn_b1  = (const float*)d_in[16];
  const float* vn_g1  = (const float*)d_in[17];
  const float* vn_be1 = (const float*)d_in[18];
  const float* vn_W2  = (const float*)d_in[19];
  const float* vn_b2  = (const float*)d_in[20];
  const float* vn_g2  = (const float*)d_in[21];
  const float* vn_be2 = (const float*)d_in[22];
  const float* vn_emb = (const float*)d_in[23];
  const float* post_W1= (const float*)d_in[24];
  const float* post_b1= (const float*)d_in[25];
  const float* post_W2= (const float*)d_in[26];
  const float* post_b2= (const float*)d_in[27];
  float* out = (float*)d_out;

  const int N    = in_sizes[2];
  const int E    = in_sizes[1] / 2;
  const int G    = out_size / H;
  const int HOPS = in_sizes[7] / (H * H);
  const int NH   = N * H;

  // workspace layout (floats)
  float* w = (float*)d_ws;
  float* buf_x  = w;  w += NH;        // persistent node features
  float* buf_t  = w;  w += N * H2;    // FFN hidden; during GCN: h (first NH) + agg (second NH)
  float* buf_h  = buf_t;
  float* buf_agg= buf_t + NH;
  float* deg    = w;  w += N;         // becomes dinv in place
  float* counts = w;  w += G;
  float* stats  = w;  w += 2 * H;
  float* scsh   = w;  w += 2 * H;
  float* pooled = w;  w += G * H;
  float* vn     = w;  w += G * H;

  const int* src = edge;
  const int* dst = edge + E;

  int gN  = (N + 255) / 256;
  int gE  = (E + 255) / 256;
  int gNH = (NH + 255) / 256;
  int gM  = (N + 63) / 64;
  int gSc = (E * H + 255) / 256;

  // degrees (with self loop) -> dinv, graph counts, vn init
  fill1_kernel<<<gN, 256, 0, stream>>>(deg, N);
  deg_count_kernel<<<gE, 256, 0, stream>>>(deg, dst, E);
  rsqrt_kernel<<<gN, 256, 0, stream>>>(deg, N);
  hipMemsetAsync(counts, 0, G * sizeof(float), stream);
  count_kernel<<<gN, 256, 0, stream>>>(counts, batch, N);
  vn_init_kernel<<<(G * H + 255) / 256, 256, 0, stream>>>(vn, vn_emb, G * H);

  // pre-FFNN
  gemm_kernel<1, 0, 1><<<dim3(gM, H2 / 64), 256, 0, stream>>>(x_in, pre_W1, pre_b1, buf_t, N, H, H2);
  gemm_kernel<1, 0, 1><<<dim3(gM, H / 64), 256, 0, stream>>>(buf_t, pre_W2, pre_b2, buf_x, N, H2, H);

  for (int i = 0; i < HOPS; i++) {
    add_vn_kernel<<<gNH, 256, 0, stream>>>(buf_x, vn, batch, NH);
    // GCN: h = x @ W
    gemm_kernel<0, 0, 0><<<dim3(gM, H / 64), 256, 0, stream>>>(buf_x, conv_W + i * H * H, nullptr, buf_h, N, H, H);
    // agg = selfloop + scatter(norm * h[src])
    selfloop_kernel<<<gNH, 256, 0, stream>>>(buf_agg, buf_h, deg, NH);
    scatter_kernel<<<gSc, 256, 0, stream>>>(buf_h, src, dst, deg, buf_agg, E);
    combine_kernel<<<gNH, 256, 0, stream>>>(buf_x, buf_agg, conv_b + i * H, NH);
    // BN
    hipMemsetAsync(stats, 0, 2 * H * sizeof(float), stream);
    bn_reduce_kernel<<<(N + 127) / 128, 256, 0, stream>>>(buf_x, stats, N);
    bn_finalize_kernel<<<1, 128, 0, stream>>>(stats, bn_g + i * H, bn_b + i * H, scsh, 1.0f / (float)N);
    bn_apply_kernel<<<gNH, 256, 0, stream>>>(buf_x, scsh, NH);
    // FFN with residual
    gemm_kernel<1, 0, 1><<<dim3(gM, H2 / 64), 256, 0, stream>>>(buf_x, ffn_W1 + i * H * H2, ffn_b1 + i * H2, buf_t, N, H, H2);
    gemm_kernel<1, 1, 1><<<dim3(gM, H / 64), 256, 0, stream>>>(buf_t, ffn_W2 + i * H2 * H, ffn_b2 + i * H, buf_x, N, H2, H);
    // virtual node update
    if (i < HOPS - 1) {
      hipMemsetAsync(pooled, 0, G * H * sizeof(float), stream);
      pool_kernel<<<gNH, 256, 0, stream>>>(pooled, buf_x, batch, NH);
      vn_mlp_kernel<<<1, 256, 0, stream>>>(vn, pooled, counts,
                                           vn_W1 + i * H * H2, vn_b1 + i * H2, vn_g1 + i * H2, vn_be1 + i * H2,
                                           vn_W2 + i * H2 * H, vn_b2 + i * H, vn_g2 + i * H, vn_be2 + i * H);
    }
  }

  // final global_add_pool + post-FFNN
  hipMemsetAsync(pooled, 0, G * H * sizeof(float), stream);
  pool_kernel<<<gNH, 256, 0, stream>>>(pooled, buf_x, batch, NH);
  post_kernel<<<1, 256, 0, stream>>>(out, pooled, post_W1, post_b1, post_W2, post_b2);
}

// Round 2
// 4624.460 us; speedup vs baseline: 1.2716x; 1.2716x over previous
//
#include <hip/hip_runtime.h>
#include <math.h>

#define H 128
#define H2 256
#define LDK 72  // LDS row stride in bf16 elements (144 B, 16B-aligned)

typedef __attribute__((ext_vector_type(8))) short short8;
typedef __attribute__((ext_vector_type(4))) float floatx4;

__device__ __forceinline__ float gelu_f(float x) {
  return 0.5f * x * (1.0f + erff(x * 0.70710678118654752440f));
}

__device__ __forceinline__ unsigned short f2b(float f) {
  union { float f; unsigned u; } c; c.f = f;
  unsigned r = c.u + 0x7fffu + ((c.u >> 16) & 1u);
  return (unsigned short)(r >> 16);
}

// ---------------- weight transpose+convert: W[b][K][N] fp32 -> WT[b][N][K] bf16 ----------------
__global__ __launch_bounds__(256) void transpose_w(const float* __restrict__ W, unsigned short* __restrict__ WT,
                                                   int K, int Ncol, int total) {
  int i = blockIdx.x * 256 + threadIdx.x;
  if (i >= total) return;
  int kn = K * Ncol;
  int b = i / kn, r = i - b * kn;
  int k = r / Ncol, n = r - k * Ncol;
  WT[b * kn + n * K + k] = f2b(W[i]);
}

// ---------------- elementwise / small kernels ----------------

__global__ __launch_bounds__(256) void fill1_kernel(float* p, int n) {
  int i = blockIdx.x * 256 + threadIdx.x;
  if (i < n) p[i] = 1.0f;
}

__global__ __launch_bounds__(256) void deg_count_kernel(float* deg, const int* __restrict__ dst, int E) {
  int i = blockIdx.x * 256 + threadIdx.x;
  if (i < E) atomicAdd(&deg[dst[i]], 1.0f);
}

__global__ __launch_bounds__(256) void rsqrt_kernel(float* p, int n) {
  int i = blockIdx.x * 256 + threadIdx.x;
  if (i < n) p[i] = rsqrtf(fmaxf(p[i], 1.0f));
}

// batch is sorted: per-thread run-length compression + LDS histogram, few atomics
__global__ __launch_bounds__(256) void count_kernel(float* counts, const int* __restrict__ batch, int N, int G) {
  __shared__ float hist[256];
  int t = threadIdx.x;
  if (t < G) hist[t] = 0.f;
  __syncthreads();
  int i0 = (blockIdx.x * 256 + t) * 16;
  int cur = -1; float run = 0.f;
  for (int j = 0; j < 16; j++) {
    int i = i0 + j;
    if (i < N) {
      int b = batch[i];
      if (b == cur) run += 1.f;
      else { if (cur >= 0) atomicAdd(&hist[cur], run); cur = b; run = 1.f; }
    }
  }
  if (cur >= 0) atomicAdd(&hist[cur], run);
  __syncthreads();
  if (t < G && hist[t] != 0.f) atomicAdd(&counts[t], hist[t]);
}

__global__ __launch_bounds__(256) void vn_init_kernel(float* vn, const float* __restrict__ emb, int n) {
  int i = blockIdx.x * 256 + threadIdx.x;
  if (i < n) vn[i] = emb[i & (H - 1)];
}

__global__ __launch_bounds__(256) void add_vn_kernel(float* __restrict__ x, const float* __restrict__ vn,
                                                     const int* __restrict__ batch, int NH) {
  int i = blockIdx.x * 256 + threadIdx.x;
  if (i < NH) x[i] += vn[batch[i >> 7] * H + (i & (H - 1))];
}

__global__ __launch_bounds__(256) void selfloop_kernel(float* __restrict__ agg, const float* __restrict__ h,
                                                       const float* __restrict__ dinv, int NH) {
  int i = blockIdx.x * 256 + threadIdx.x;
  if (i < NH) { float d = dinv[i >> 7]; agg[i] = h[i] * d * d; }
}

__global__ __launch_bounds__(256) void scatter_kernel(const float* __restrict__ h, const int* __restrict__ src,
                                                      const int* __restrict__ dst, const float* __restrict__ dinv,
                                                      float* __restrict__ agg, int E) {
  int i = blockIdx.x * 256 + threadIdx.x;
  int e = i >> 7;
  if (e < E) {
    int c = i & (H - 1);
    int s = src[e], d = dst[e];
    atomicAdd(&agg[d * H + c], h[s * H + c] * dinv[s] * dinv[d]);
  }
}

__global__ __launch_bounds__(256) void combine_kernel(float* __restrict__ x, const float* __restrict__ agg,
                                                      const float* __restrict__ bias, int NH) {
  int i = blockIdx.x * 256 + threadIdx.x;
  if (i < NH) x[i] += agg[i] + bias[i & (H - 1)];
}

__global__ __launch_bounds__(256) void bn_reduce_kernel(const float* __restrict__ x, float* __restrict__ stats, int N) {
  __shared__ float ls[256], ls2[256];
  int t = threadIdx.x;
  int c = t & (H - 1);
  int r0 = blockIdx.x * 128 + (t >> 7);
  float s = 0.f, s2 = 0.f;
  for (int k = 0; k < 64; k++) {
    int r = r0 + k * 2;
    if (r < N) { float v = x[r * H + c]; s += v; s2 += v * v; }
  }
  ls[t] = s; ls2[t] = s2;
  __syncthreads();
  if (t < 128) {
    atomicAdd(&stats[c], ls[t] + ls[t + 128]);
    atomicAdd(&stats[H + c], ls2[t] + ls2[t + 128]);
  }
}

__global__ __launch_bounds__(128) void bn_finalize_kernel(const float* __restrict__ stats, const float* __restrict__ g,
                                                          const float* __restrict__ b, float* __restrict__ scsh,
                                                          float invN) {
  int c = threadIdx.x;  // 128 threads
  float m = stats[c] * invN;
  float v = stats[H + c] * invN - m * m;
  float sc = rsqrtf(v + 1e-5f) * g[c];
  scsh[c] = sc;
  scsh[H + c] = b[c] - m * sc;
}

__global__ __launch_bounds__(256) void pool_kernel(float* __restrict__ pooled, const float* __restrict__ x,
                                                   const int* __restrict__ batch, int NH) {
  int i = blockIdx.x * 256 + threadIdx.x;
  if (i < NH) atomicAdd(&pooled[batch[i >> 7] * H + (i & (H - 1))], x[i]);
}

// ---------------- bf16 MFMA GEMM ----------------
// C[M x Ncol] = epi(A[M x K] @ B + bias), B given pre-transposed bf16 BT[Ncol][K].
// 64x64 block tile, 256 threads = 4 waves; wave w computes rows [16w,16w+16) x 64 cols
// via 4 x mfma_f32_16x16x32_bf16 per 32-k step. BK=64.
// ACT: gelu. RES: 0 none, 1 += C, 2 += resid*sc+sh (BN fused residual).
// ASCALE: apply scshA (BN scale/shift over K features) to A while staging.
template <int ACT, int RES, int HASBIAS, int ASCALE>
__global__ __launch_bounds__(256) void gemm_mfma(const float* __restrict__ A,
                                                 const unsigned short* __restrict__ BT,
                                                 const float* __restrict__ bias,
                                                 const float* __restrict__ scshA,
                                                 const float* __restrict__ scshR,
                                                 const float* __restrict__ resid,
                                                 float* __restrict__ C, int M, int K, int Ncol) {
  __shared__ unsigned short As[64 * LDK];
  __shared__ unsigned short Bs[64 * LDK];
  int tid = threadIdx.x;
  int lane = tid & 63, w = tid >> 6;
  int row0 = blockIdx.x * 64, col0 = blockIdx.y * 64;

  floatx4 acc[4];
#pragma unroll
  for (int t = 0; t < 4; t++) acc[t] = (floatx4)0.f;

  int ar = tid >> 4;          // A staging: row within 16-row slab
  int ac4 = (tid & 15) * 4;   // A staging: k offset (float4)
  int bn = tid >> 3;          // B staging: col-row within 32-slab
  int bk8 = (tid & 7) * 8;    // B staging: k offset (8 bf16 = 16B)

  int mrow = lane & 15;       // MFMA A/B row (m or n) within tile
  int quad = lane >> 4;       // MFMA quad -> k-group / output row group

  for (int k0 = 0; k0 < K; k0 += 64) {
    // stage A (fp32 -> bf16, optional BN)
#pragma unroll
    for (int j = 0; j < 4; j++) {
      int r = j * 16 + ar;
      int gr = row0 + r;
      floatx4 v;
      if (gr < M) v = *(const floatx4*)&A[(long)gr * K + k0 + ac4];
      else v = (floatx4)0.f;
      if (ASCALE) {
        floatx4 sc = *(const floatx4*)&scshA[k0 + ac4];
        floatx4 sh = *(const floatx4*)&scshA[K + k0 + ac4];
        v = v * sc + sh;
      }
      unsigned long long p = (unsigned long long)f2b(v.x)
                           | ((unsigned long long)f2b(v.y) << 16)
                           | ((unsigned long long)f2b(v.z) << 32)
                           | ((unsigned long long)f2b(v.w) << 48);
      *(unsigned long long*)&As[r * LDK + ac4] = p;
    }
    // stage B (already bf16, already [n][k])
#pragma unroll
    for (int j = 0; j < 2; j++) {
      int n = j * 32 + bn;
      short8 v = *(const short8*)&BT[(long)(col0 + n) * K + k0 + bk8];
      *(short8*)&Bs[n * LDK + bk8] = v;
    }
    __syncthreads();
#pragma unroll
    for (int kk = 0; kk < 2; kk++) {
      int kb = kk * 32 + quad * 8;
      short8 af = *(const short8*)&As[(w * 16 + mrow) * LDK + kb];
#pragma unroll
      for (int t = 0; t < 4; t++) {
        short8 bf = *(const short8*)&Bs[(t * 16 + mrow) * LDK + kb];
        acc[t] = __builtin_amdgcn_mfma_f32_16x16x32_bf16(af, bf, acc[t], 0, 0, 0);
      }
    }
    __syncthreads();
  }

  // epilogue: C/D layout col = lane&15, row = quad*4 + i
  int cn = lane & 15;
#pragma unroll
  for (int t = 0; t < 4; t++) {
    int c = col0 + t * 16 + cn;
    float b = HASBIAS ? bias[c] : 0.f;
    float rsc = 0.f, rsh = 0.f;
    if (RES == 2) { rsc = scshR[c]; rsh = scshR[H + c]; }
#pragma unroll
    for (int i = 0; i < 4; i++) {
      int r = row0 + w * 16 + quad * 4 + i;
      if (r < M) {
        float v = acc[t][i] + b;
        if (ACT) v = gelu_f(v);
        long off = (long)r * Ncol + c;
        if (RES == 1) v += C[off];
        if (RES == 2) v += resid[off] * rsc + rsh;
        C[off] = v;
      }
    }
  }
}

// ---------------- single-block 64-row MLPs ----------------
__global__ __launch_bounds__(256) void vn_mlp_kernel(float* __restrict__ vn, const float* __restrict__ pooled,
                                                     const float* __restrict__ counts,
                                                     const float* __restrict__ W1, const float* __restrict__ b1,
                                                     const float* __restrict__ g1, const float* __restrict__ be1,
                                                     const float* __restrict__ W2, const float* __restrict__ b2,
                                                     const float* __restrict__ g2, const float* __restrict__ be2) {
  __shared__ float sh[64 * 256];
  int t = threadIdx.x;
  for (int idx = t; idx < 64 * H; idx += 256) {
    int g = idx >> 7;
    sh[idx] = vn[idx] + pooled[idx] / fmaxf(counts[g], 1.0f);
  }
  __syncthreads();

  float col[64];
  float bj = b1[t];
#pragma unroll
  for (int g = 0; g < 64; g++) col[g] = bj;
  for (int k0 = 0; k0 < H; k0 += 4) {
    float w0 = W1[(k0 + 0) * H2 + t];
    float w1 = W1[(k0 + 1) * H2 + t];
    float w2 = W1[(k0 + 2) * H2 + t];
    float w3 = W1[(k0 + 3) * H2 + t];
#pragma unroll
    for (int g = 0; g < 64; g++) {
      float4 v = *(const float4*)&sh[g * H + k0];
      col[g] += v.x * w0 + v.y * w1 + v.z * w2 + v.w * w3;
    }
  }
  {
    float s = 0.f, s2 = 0.f;
#pragma unroll
    for (int g = 0; g < 64; g++) { s += col[g]; s2 += col[g] * col[g]; }
    float m = s * (1.f / 64.f);
    float var = s2 * (1.f / 64.f) - m * m;
    float sc = rsqrtf(var + 1e-5f) * g1[t];
    float shf = be1[t];
#pragma unroll
    for (int g = 0; g < 64; g++) col[g] = gelu_f((col[g] - m) * sc + shf);
  }
  __syncthreads();
#pragma unroll
  for (int g = 0; g < 64; g++) sh[g * H2 + t] = col[g];
  __syncthreads();

  if (t < H) {
    float c2[64];
    float bj2 = b2[t];
#pragma unroll
    for (int g = 0; g < 64; g++) c2[g] = bj2;
    for (int k0 = 0; k0 < H2; k0 += 4) {
      float w0 = W2[(k0 + 0) * H + t];
      float w1 = W2[(k0 + 1) * H + t];
      float w2 = W2[(k0 + 2) * H + t];
      float w3 = W2[(k0 + 3) * H + t];
#pragma unroll
      for (int g = 0; g < 64; g++) {
        float4 v = *(const float4*)&sh[g * H2 + k0];
        c2[g] += v.x * w0 + v.y * w1 + v.z * w2 + v.w * w3;
      }
    }
    float s = 0.f, s2 = 0.f;
#pragma unroll
    for (int g = 0; g < 64; g++) { s += c2[g]; s2 += c2[g] * c2[g]; }
    float m = s * (1.f / 64.f);
    float var = s2 * (1.f / 64.f) - m * m;
    float sc = rsqrtf(var + 1e-5f) * g2[t];
    float shf = be2[t];
#pragma unroll
    for (int g = 0; g < 64; g++) vn[g * H + t] = gelu_f((c2[g] - m) * sc + shf);
  }
}

__global__ __launch_bounds__(256) void post_kernel(float* __restrict__ out, const float* __restrict__ pooled,
                                                   const float* __restrict__ W1, const float* __restrict__ b1,
                                                   const float* __restrict__ W2, const float* __restrict__ b2) {
  __shared__ float sh[64 * 256];
  int t = threadIdx.x;
  for (int idx = t; idx < 64 * H; idx += 256) sh[idx] = pooled[idx];
  __syncthreads();

  float col[64];
  float bj = b1[t];
#pragma unroll
  for (int g = 0; g < 64; g++) col[g] = bj;
  for (int k0 = 0; k0 < H; k0 += 4) {
    float w0 = W1[(k0 + 0) * H2 + t];
    float w1 = W1[(k0 + 1) * H2 + t];
    float w2 = W1[(k0 + 2) * H2 + t];
    float w3 = W1[(k0 + 3) * H2 + t];
#pragma unroll
    for (int g = 0; g < 64; g++) {
      float4 v = *(const float4*)&sh[g * H + k0];
      col[g] += v.x * w0 + v.y * w1 + v.z * w2 + v.w * w3;
    }
  }
#pragma unroll
  for (int g = 0; g < 64; g++) col[g] = gelu_f(col[g]);
  __syncthreads();
#pragma unroll
  for (int g = 0; g < 64; g++) sh[g * H2 + t] = col[g];
  __syncthreads();

  if (t < H) {
    float c2[64];
    float bj2 = b2[t];
#pragma unroll
    for (int g = 0; g < 64; g++) c2[g] = bj2;
    for (int k0 = 0; k0 < H2; k0 += 4) {
      float w0 = W2[(k0 + 0) * H + t];
      float w1 = W2[(k0 + 1) * H + t];
      float w2 = W2[(k0 + 2) * H + t];
      float w3 = W2[(k0 + 3) * H + t];
#pragma unroll
      for (int g = 0; g < 64; g++) {
        float4 v = *(const float4*)&sh[g * H2 + k0];
        c2[g] += v.x * w0 + v.y * w1 + v.z * w2 + v.w * w3;
      }
    }
#pragma unroll
    for (int g = 0; g < 64; g++) out[g * H + t] = gelu_f(c2[g]);
  }
}

// ---------------- host launch ----------------

extern "C" void kernel_launch(void* const* d_in, const int* in_sizes, int n_in,
                              void* d_out, int out_size, void* d_ws, size_t ws_size,
                              hipStream_t stream) {
  const float* x_in   = (const float*)d_in[0];
  const int*   edge   = (const int*)d_in[1];
  const int*   batch  = (const int*)d_in[2];
  const float* pre_W1 = (const float*)d_in[3];
  const float* pre_b1 = (const float*)d_in[4];
  const float* pre_W2 = (const float*)d_in[5];
  const float* pre_b2 = (const float*)d_in[6];
  const float* conv_W = (const float*)d_in[7];
  const float* conv_b = (const float*)d_in[8];
  const float* bn_g   = (const float*)d_in[9];
  const float* bn_b   = (const float*)d_in[10];
  const float* ffn_W1 = (const float*)d_in[11];
  const float* ffn_b1 = (const float*)d_in[12];
  const float* ffn_W2 = (const float*)d_in[13];
  const float* ffn_b2 = (const float*)d_in[14];
  const float* vn_W1  = (const float*)d_in[15];
  const float* vn_b1  = (const float*)d_in[16];
  const float* vn_g1  = (const float*)d_in[17];
  const float* vn_be1 = (const float*)d_in[18];
  const float* vn_W2  = (const float*)d_in[19];
  const float* vn_b2  = (const float*)d_in[20];
  const float* vn_g2  = (const float*)d_in[21];
  const float* vn_be2 = (const float*)d_in[22];
  const float* vn_emb = (const float*)d_in[23];
  const float* post_W1= (const float*)d_in[24];
  const float* post_b1= (const float*)d_in[25];
  const float* post_W2= (const float*)d_in[26];
  const float* post_b2= (const float*)d_in[27];
  float* out = (float*)d_out;

  const int N    = in_sizes[2];
  const int E    = in_sizes[1] / 2;
  const int G    = out_size / H;
  const int HOPS = in_sizes[7] / (H * H);
  const int NH   = N * H;

  // workspace layout (floats)
  float* w = (float*)d_ws;
  float* buf_x  = w;  w += NH;        // persistent node features
  float* buf_t  = w;  w += N * H2;    // FFN hidden; during GCN: h + agg
  float* buf_h  = buf_t;
  float* buf_agg= buf_t + NH;
  float* deg    = w;  w += N;         // becomes dinv in place
  float* counts = w;  w += G;
  float* stats  = w;  w += 2 * H;
  float* scsh   = w;  w += 2 * H;
  float* pooled = w;  w += G * H;
  float* vn     = w;  w += G * H;
  // bf16 transposed weights
  unsigned short* wt = (unsigned short*)w;
  unsigned short* preW1T = wt;                 wt += H * H2;
  unsigned short* preW2T = wt;                 wt += H2 * H;
  unsigned short* convT  = wt;                 wt += HOPS * H * H;
  unsigned short* ffn1T  = wt;                 wt += HOPS * H * H2;
  unsigned short* ffn2T  = wt;                 wt += HOPS * H2 * H;

  const int* src = edge;
  const int* dst = edge + E;

  int gN  = (N + 255) / 256;
  int gE  = (E + 255) / 256;
  int gNH = (NH + 255) / 256;
  int gM  = (N + 63) / 64;
  int gSc = (E * H + 255) / 256;

  // weight transposes (per call: ws is re-poisoned)
  transpose_w<<<(H * H2 + 255) / 256, 256, 0, stream>>>(pre_W1, preW1T, H, H2, H * H2);
  transpose_w<<<(H2 * H + 255) / 256, 256, 0, stream>>>(pre_W2, preW2T, H2, H, H2 * H);
  transpose_w<<<(HOPS * H * H + 255) / 256, 256, 0, stream>>>(conv_W, convT, H, H, HOPS * H * H);
  transpose_w<<<(HOPS * H * H2 + 255) / 256, 256, 0, stream>>>(ffn_W1, ffn1T, H, H2, HOPS * H * H2);
  transpose_w<<<(HOPS * H2 * H + 255) / 256, 256, 0, stream>>>(ffn_W2, ffn2T, H2, H, HOPS * H2 * H);

  // degrees (with self loop) -> dinv, graph counts, vn init
  fill1_kernel<<<gN, 256, 0, stream>>>(deg, N);
  deg_count_kernel<<<gE, 256, 0, stream>>>(deg, dst, E);
  rsqrt_kernel<<<gN, 256, 0, stream>>>(deg, N);
  hipMemsetAsync(counts, 0, G * sizeof(float), stream);
  count_kernel<<<(N + 256 * 16 - 1) / (256 * 16), 256, 0, stream>>>(counts, batch, N, G);
  vn_init_kernel<<<(G * H + 255) / 256, 256, 0, stream>>>(vn, vn_emb, G * H);

  // pre-FFNN
  gemm_mfma<1, 0, 1, 0><<<dim3(gM, H2 / 64), 256, 0, stream>>>(x_in, preW1T, pre_b1, nullptr, nullptr, nullptr, buf_t, N, H, H2);
  gemm_mfma<1, 0, 1, 0><<<dim3(gM, H / 64), 256, 0, stream>>>(buf_t, preW2T, pre_b2, nullptr, nullptr, nullptr, buf_x, N, H2, H);

  for (int i = 0; i < HOPS; i++) {
    add_vn_kernel<<<gNH, 256, 0, stream>>>(buf_x, vn, batch, NH);
    // GCN: h = x @ W
    gemm_mfma<0, 0, 0, 0><<<dim3(gM, H / 64), 256, 0, stream>>>(buf_x, convT + i * H * H, nullptr, nullptr, nullptr, nullptr, buf_h, N, H, H);
    // agg = selfloop + scatter(norm * h[src])
    selfloop_kernel<<<gNH, 256, 0, stream>>>(buf_agg, buf_h, deg, NH);
    scatter_kernel<<<gSc, 256, 0, stream>>>(buf_h, src, dst, deg, buf_agg, E);
    combine_kernel<<<gNH, 256, 0, stream>>>(buf_x, buf_agg, conv_b + i * H, NH);
    // BN stats (apply is fused into the FFN GEMMs)
    hipMemsetAsync(stats, 0, 2 * H * sizeof(float), stream);
    bn_reduce_kernel<<<(N + 127) / 128, 256, 0, stream>>>(buf_x, stats, N);
    bn_finalize_kernel<<<1, 128, 0, stream>>>(stats, bn_g + i * H, bn_b + i * H, scsh, 1.0f / (float)N);
    // FFN: t = gelu(bn(x) @ W1 + b1); x = gelu(t @ W2 + b2) + bn(x)
    gemm_mfma<1, 0, 1, 1><<<dim3(gM, H2 / 64), 256, 0, stream>>>(buf_x, ffn1T + i * H * H2, ffn_b1 + i * H2, scsh, nullptr, nullptr, buf_t, N, H, H2);
    gemm_mfma<1, 2, 1, 0><<<dim3(gM, H / 64), 256, 0, stream>>>(buf_t, ffn2T + i * H2 * H, ffn_b2 + i * H, nullptr, scsh, buf_x, buf_x, N, H2, H);
    // virtual node update
    if (i < HOPS - 1) {
      hipMemsetAsync(pooled, 0, G * H * sizeof(float), stream);
      pool_kernel<<<gNH, 256, 0, stream>>>(pooled, buf_x, batch, NH);
      vn_mlp_kernel<<<1, 256, 0, stream>>>(vn, pooled, counts,
                                           vn_W1 + i * H * H2, vn_b1 + i * H2, vn_g1 + i * H2, vn_be1 + i * H2,
                                           vn_W2 + i * H2 * H, vn_b2 + i * H, vn_g2 + i * H, vn_be2 + i * H);
    }
  }

  // final global_add_pool + post-FFNN
  hipMemsetAsync(pooled, 0, G * H * sizeof(float), stream);
  pool_kernel<<<gNH, 256, 0, stream>>>(pooled, buf_x, batch, NH);
  post_kernel<<<1, 256, 0, stream>>>(out, pooled, post_W1, post_b1, post_W2, post_b2);
}

// Round 3
// 3170.068 us; speedup vs baseline: 1.8550x; 1.4588x over previous
//
#include <hip/hip_runtime.h>
#include <math.h>

#define H 128
#define H2 256
#define LDK 72  // LDS row stride in bf16 elements (144 B, 16B-aligned)

typedef __attribute__((ext_vector_type(8))) short short8;
typedef __attribute__((ext_vector_type(4))) float floatx4;

__device__ __forceinline__ float gelu_f(float x) {
  return 0.5f * x * (1.0f + erff(x * 0.70710678118654752440f));
}

__device__ __forceinline__ unsigned short f2b(float f) {
  union { float f; unsigned u; } c; c.f = f;
  unsigned r = c.u + 0x7fffu + ((c.u >> 16) & 1u);
  return (unsigned short)(r >> 16);
}

// ---------------- weight transpose+convert: W[b][K][N] fp32 -> WT[b][N][K] bf16 ----------------
__global__ __launch_bounds__(256) void transpose_w(const float* __restrict__ W, unsigned short* __restrict__ WT,
                                                   int K, int Ncol, int total) {
  int i = blockIdx.x * 256 + threadIdx.x;
  if (i >= total) return;
  int kn = K * Ncol;
  int b = i / kn, r = i - b * kn;
  int k = r / Ncol, n = r - k * Ncol;
  WT[b * kn + n * K + k] = f2b(W[i]);
}

// ---------------- CSR build ----------------

__global__ __launch_bounds__(256) void hist_kernel(int* __restrict__ cnt, const int* __restrict__ dst, int E) {
  int i = blockIdx.x * 256 + threadIdx.x;
  if (i < E) atomicAdd(&cnt[dst[i]], 1);
}

__global__ __launch_bounds__(256) void dinv_kernel(float* __restrict__ dinv, const int* __restrict__ cnt, int N) {
  int i = blockIdx.x * 256 + threadIdx.x;
  if (i < N) dinv[i] = rsqrtf((float)cnt[i] + 1.0f);  // +1 self loop
}

// single-block exclusive scan of cnt[0..N) -> row_ptr, row_ptr[N]=E
__global__ __launch_bounds__(1024) void scan_kernel(const int* __restrict__ cnt, int* __restrict__ row_ptr,
                                                    int N, int E) {
  __shared__ int part[1024];
  int t = threadIdx.x;
  int per = (N + 1023) / 1024;
  int beg = t * per;
  int end = beg + per; if (end > N) end = N;
  int s = 0;
  for (int i = beg; i < end; i++) s += cnt[i];
  part[t] = s;
  __syncthreads();
  for (int off = 1; off < 1024; off <<= 1) {
    int v = (t >= off) ? part[t - off] : 0;
    __syncthreads();
    part[t] += v;
    __syncthreads();
  }
  int prefix = (t == 0) ? 0 : part[t - 1];
  for (int i = beg; i < end; i++) {
    row_ptr[i] = prefix;
    prefix += cnt[i];
  }
  if (t == 1023) row_ptr[N] = E;
}

__global__ __launch_bounds__(256) void build_csr_kernel(const int* __restrict__ src, const int* __restrict__ dst,
                                                        const int* __restrict__ row_ptr, int* __restrict__ cursor,
                                                        const float* __restrict__ dinv,
                                                        int* __restrict__ csr_src, float* __restrict__ csr_norm,
                                                        int E) {
  int i = blockIdx.x * 256 + threadIdx.x;
  if (i < E) {
    int s = src[i], d = dst[i];
    int pos = row_ptr[d] + atomicAdd(&cursor[d], 1);
    csr_src[pos] = s;
    csr_norm[pos] = dinv[s] * dinv[d];
  }
}

// ---------------- small setup kernels ----------------

// batch is sorted: per-thread run-length compression + LDS histogram
__global__ __launch_bounds__(256) void count_kernel(float* counts, const int* __restrict__ batch, int N, int G) {
  __shared__ float hist[256];
  int t = threadIdx.x;
  if (t < G) hist[t] = 0.f;
  __syncthreads();
  int i0 = (blockIdx.x * 256 + t) * 16;
  int cur = -1; float run = 0.f;
  for (int j = 0; j < 16; j++) {
    int i = i0 + j;
    if (i < N) {
      int b = batch[i];
      if (b == cur) run += 1.f;
      else { if (cur >= 0) atomicAdd(&hist[cur], run); cur = b; run = 1.f; }
    }
  }
  if (cur >= 0) atomicAdd(&hist[cur], run);
  __syncthreads();
  if (t < G && hist[t] != 0.f) atomicAdd(&counts[t], hist[t]);
}

__global__ __launch_bounds__(256) void vn_init_kernel(float* vn, const float* __restrict__ emb, int n) {
  int i = blockIdx.x * 256 + threadIdx.x;
  if (i < n) vn[i] = emb[i & (H - 1)];
}

// ---------------- fused gather aggregation ----------------
// x[node] = x[node] + vn[batch[node]] + bias + h[node]*dinv^2 + sum_edges h[src]*norm
// one wave per node, lane handles 2 cols (float2)
__global__ __launch_bounds__(256) void gather_agg(const float* __restrict__ h, const int* __restrict__ csr_src,
                                                  const float* __restrict__ csr_norm, const int* __restrict__ row_ptr,
                                                  const float* __restrict__ dinv, const float* __restrict__ vn,
                                                  const int* __restrict__ batch, const float* __restrict__ bias,
                                                  float* __restrict__ x, int N) {
  int node = blockIdx.x * 4 + (threadIdx.x >> 6);
  if (node >= N) return;
  int lane = threadIdx.x & 63;
  int c = lane * 2;
  float di = dinv[node];
  float2 hv = *(const float2*)&h[(long)node * H + c];
  float ax = hv.x * di * di, ay = hv.y * di * di;
  int beg = row_ptr[node], end = row_ptr[node + 1];
  for (int e = beg; e < end; e++) {
    int s = csr_src[e];
    float wgt = csr_norm[e];
    float2 v = *(const float2*)&h[(long)s * H + c];
    ax += v.x * wgt; ay += v.y * wgt;
  }
  int b = batch[node];
  float2 xo = *(const float2*)&x[(long)node * H + c];
  float2 vv = *(const float2*)&vn[b * H + c];
  float2 bi = *(const float2*)&bias[c];
  float2 r;
  r.x = ax + xo.x + vv.x + bi.x;
  r.y = ay + xo.y + vv.y + bi.y;
  *(float2*)&x[(long)node * H + c] = r;
}

// ---------------- BN stats ----------------

__global__ __launch_bounds__(256) void bn_reduce_kernel(const float* __restrict__ x, float* __restrict__ stats, int N) {
  __shared__ float ls[256], ls2[256];
  int t = threadIdx.x;
  int c = t & (H - 1);
  int r0 = blockIdx.x * 128 + (t >> 7);
  float s = 0.f, s2 = 0.f;
  for (int k = 0; k < 64; k++) {
    int r = r0 + k * 2;
    if (r < N) { float v = x[r * H + c]; s += v; s2 += v * v; }
  }
  ls[t] = s; ls2[t] = s2;
  __syncthreads();
  if (t < 128) {
    atomicAdd(&stats[c], ls[t] + ls[t + 128]);
    atomicAdd(&stats[H + c], ls2[t] + ls2[t + 128]);
  }
}

__global__ __launch_bounds__(128) void bn_finalize_kernel(const float* __restrict__ stats, const float* __restrict__ g,
                                                          const float* __restrict__ b, float* __restrict__ scsh,
                                                          float invN) {
  int c = threadIdx.x;
  float m = stats[c] * invN;
  float v = stats[H + c] * invN - m * m;
  float sc = rsqrtf(v + 1e-5f) * g[c];
  scsh[c] = sc;
  scsh[H + c] = b[c] - m * sc;
}

// ---------------- pooling (run-length over sorted batch) ----------------
__global__ __launch_bounds__(256) void pool_kernel(float* __restrict__ pooled, const float* __restrict__ x,
                                                   const int* __restrict__ batch, int N) {
  int c = threadIdx.x & 127;
  int slab = threadIdx.x >> 7;
  int r0 = blockIdx.x * 128 + slab;
  float acc = 0.f;
  int cur = -1;
  for (int k = 0; k < 64; k++) {
    int r = r0 + k * 2;
    if (r >= N) break;
    int b = batch[r];
    if (b != cur) {
      if (cur >= 0) atomicAdd(&pooled[cur * H + c], acc);
      cur = b; acc = 0.f;
    }
    acc += x[(long)r * H + c];
  }
  if (cur >= 0) atomicAdd(&pooled[cur * H + c], acc);
}

// ---------------- bf16 MFMA GEMM ----------------
// C[M x Ncol] = epi(A'[M x K] @ B + bias), B pre-transposed bf16 BT[Ncol][K].
// Tile: 64 rows x NT cols (NT = full Ncol), 256 threads = 4 waves.
// A' = A (optionally *sc+sh over K features (ASCALE), optionally + vn[batch[row]] (AVN)).
// ACT: gelu. RES: 0 none, 1 += C, 2 += resid*sc+sh (BN fused residual).
template <int NT, int ACT, int RES, int HASBIAS, int ASCALE, int AVN>
__global__ __launch_bounds__(256) void gemm_mfma(const float* __restrict__ A,
                                                 const unsigned short* __restrict__ BT,
                                                 const float* __restrict__ bias,
                                                 const float* __restrict__ scshA,
                                                 const float* __restrict__ scshR,
                                                 const float* __restrict__ resid,
                                                 const float* __restrict__ vn,
                                                 const int* __restrict__ batch,
                                                 float* __restrict__ C, int M, int K, int Ncol) {
  __shared__ unsigned short As[64 * LDK];
  __shared__ unsigned short Bs[NT * LDK];
  int tid = threadIdx.x;
  int lane = tid & 63, w = tid >> 6;
  int row0 = blockIdx.x * 64;

  floatx4 acc[NT / 16];
#pragma unroll
  for (int t = 0; t < NT / 16; t++) acc[t] = (floatx4)0.f;

  int ar = tid >> 4;          // A staging: row within 16-row slab
  int ac4 = (tid & 15) * 4;   // A staging: k offset (float4)
  int bn = tid >> 3;          // B staging: col within 32-slab
  int bk8 = (tid & 7) * 8;    // B staging: k offset (8 bf16)

  int mrow = lane & 15;
  int quad = lane >> 4;

  for (int k0 = 0; k0 < K; k0 += 64) {
#pragma unroll
    for (int j = 0; j < 4; j++) {
      int r = j * 16 + ar;
      int gr = row0 + r;
      floatx4 v;
      if (gr < M) v = *(const floatx4*)&A[(long)gr * K + k0 + ac4];
      else v = (floatx4)0.f;
      if (ASCALE) {
        floatx4 sc = *(const floatx4*)&scshA[k0 + ac4];
        floatx4 sh = *(const floatx4*)&scshA[K + k0 + ac4];
        v = v * sc + sh;
      }
      if (AVN) {
        if (gr < M) {
          int b = batch[gr];
          floatx4 vv = *(const floatx4*)&vn[b * H + k0 + ac4];
          v = v + vv;
        }
      }
      unsigned long long p = (unsigned long long)f2b(v.x)
                           | ((unsigned long long)f2b(v.y) << 16)
                           | ((unsigned long long)f2b(v.z) << 32)
                           | ((unsigned long long)f2b(v.w) << 48);
      *(unsigned long long*)&As[r * LDK + ac4] = p;
    }
#pragma unroll
    for (int j = 0; j < NT / 32; j++) {
      int n = j * 32 + bn;
      short8 v = *(const short8*)&BT[(long)n * K + k0 + bk8];
      *(short8*)&Bs[n * LDK + bk8] = v;
    }
    __syncthreads();
#pragma unroll
    for (int kk = 0; kk < 2; kk++) {
      int kb = kk * 32 + quad * 8;
      short8 af = *(const short8*)&As[(w * 16 + mrow) * LDK + kb];
#pragma unroll
      for (int t = 0; t < NT / 16; t++) {
        short8 bf = *(const short8*)&Bs[(t * 16 + mrow) * LDK + kb];
        acc[t] = __builtin_amdgcn_mfma_f32_16x16x32_bf16(af, bf, acc[t], 0, 0, 0);
      }
    }
    __syncthreads();
  }

  int cn = lane & 15;
#pragma unroll
  for (int t = 0; t < NT / 16; t++) {
    int c = t * 16 + cn;
    float b = HASBIAS ? bias[c] : 0.f;
    float rsc = 0.f, rsh = 0.f;
    if (RES == 2) { rsc = scshR[c]; rsh = scshR[H + c]; }
#pragma unroll
    for (int i = 0; i < 4; i++) {
      int r = row0 + w * 16 + quad * 4 + i;
      if (r < M) {
        float v = acc[t][i] + b;
        if (ACT) v = gelu_f(v);
        long off = (long)r * Ncol + c;
        if (RES == 1) v += C[off];
        if (RES == 2) v += resid[off] * rsc + rsh;
        C[off] = v;
      }
    }
  }
}

// ---------------- single-block 64-row MLPs ----------------
__global__ __launch_bounds__(256) void vn_mlp_kernel(float* __restrict__ vn, const float* __restrict__ pooled,
                                                     const float* __restrict__ counts,
                                                     const float* __restrict__ W1, const float* __restrict__ b1,
                                                     const float* __restrict__ g1, const float* __restrict__ be1,
                                                     const float* __restrict__ W2, const float* __restrict__ b2,
                                                     const float* __restrict__ g2, const float* __restrict__ be2) {
  __shared__ float sh[64 * 256];
  int t = threadIdx.x;
  for (int idx = t; idx < 64 * H; idx += 256) {
    int g = idx >> 7;
    sh[idx] = vn[idx] + pooled[idx] / fmaxf(counts[g], 1.0f);
  }
  __syncthreads();

  float col[64];
  float bj = b1[t];
#pragma unroll
  for (int g = 0; g < 64; g++) col[g] = bj;
  for (int k0 = 0; k0 < H; k0 += 4) {
    float w0 = W1[(k0 + 0) * H2 + t];
    float w1 = W1[(k0 + 1) * H2 + t];
    float w2 = W1[(k0 + 2) * H2 + t];
    float w3 = W1[(k0 + 3) * H2 + t];
#pragma unroll
    for (int g = 0; g < 64; g++) {
      float4 v = *(const float4*)&sh[g * H + k0];
      col[g] += v.x * w0 + v.y * w1 + v.z * w2 + v.w * w3;
    }
  }
  {
    float s = 0.f, s2 = 0.f;
#pragma unroll
    for (int g = 0; g < 64; g++) { s += col[g]; s2 += col[g] * col[g]; }
    float m = s * (1.f / 64.f);
    float var = s2 * (1.f / 64.f) - m * m;
    float sc = rsqrtf(var + 1e-5f) * g1[t];
    float shf = be1[t];
#pragma unroll
    for (int g = 0; g < 64; g++) col[g] = gelu_f((col[g] - m) * sc + shf);
  }
  __syncthreads();
#pragma unroll
  for (int g = 0; g < 64; g++) sh[g * H2 + t] = col[g];
  __syncthreads();

  if (t < H) {
    float c2[64];
    float bj2 = b2[t];
#pragma unroll
    for (int g = 0; g < 64; g++) c2[g] = bj2;
    for (int k0 = 0; k0 < H2; k0 += 4) {
      float w0 = W2[(k0 + 0) * H + t];
      float w1 = W2[(k0 + 1) * H + t];
      float w2 = W2[(k0 + 2) * H + t];
      float w3 = W2[(k0 + 3) * H + t];
#pragma unroll
      for (int g = 0; g < 64; g++) {
        float4 v = *(const float4*)&sh[g * H2 + k0];
        c2[g] += v.x * w0 + v.y * w1 + v.z * w2 + v.w * w3;
      }
    }
    float s = 0.f, s2 = 0.f;
#pragma unroll
    for (int g = 0; g < 64; g++) { s += c2[g]; s2 += c2[g] * c2[g]; }
    float m = s * (1.f / 64.f);
    float var = s2 * (1.f / 64.f) - m * m;
    float sc = rsqrtf(var + 1e-5f) * g2[t];
    float shf = be2[t];
#pragma unroll
    for (int g = 0; g < 64; g++) vn[g * H + t] = gelu_f((c2[g] - m) * sc + shf);
  }
}

__global__ __launch_bounds__(256) void post_kernel(float* __restrict__ out, const float* __restrict__ pooled,
                                                   const float* __restrict__ W1, const float* __restrict__ b1,
                                                   const float* __restrict__ W2, const float* __restrict__ b2) {
  __shared__ float sh[64 * 256];
  int t = threadIdx.x;
  for (int idx = t; idx < 64 * H; idx += 256) sh[idx] = pooled[idx];
  __syncthreads();

  float col[64];
  float bj = b1[t];
#pragma unroll
  for (int g = 0; g < 64; g++) col[g] = bj;
  for (int k0 = 0; k0 < H; k0 += 4) {
    float w0 = W1[(k0 + 0) * H2 + t];
    float w1 = W1[(k0 + 1) * H2 + t];
    float w2 = W1[(k0 + 2) * H2 + t];
    float w3 = W1[(k0 + 3) * H2 + t];
#pragma unroll
    for (int g = 0; g < 64; g++) {
      float4 v = *(const float4*)&sh[g * H + k0];
      col[g] += v.x * w0 + v.y * w1 + v.z * w2 + v.w * w3;
    }
  }
#pragma unroll
  for (int g = 0; g < 64; g++) col[g] = gelu_f(col[g]);
  __syncthreads();
#pragma unroll
  for (int g = 0; g < 64; g++) sh[g * H2 + t] = col[g];
  __syncthreads();

  if (t < H) {
    float c2[64];
    float bj2 = b2[t];
#pragma unroll
    for (int g = 0; g < 64; g++) c2[g] = bj2;
    for (int k0 = 0; k0 < H2; k0 += 4) {
      float w0 = W2[(k0 + 0) * H + t];
      float w1 = W2[(k0 + 1) * H + t];
      float w2 = W2[(k0 + 2) * H + t];
      float w3 = W2[(k0 + 3) * H + t];
#pragma unroll
      for (int g = 0; g < 64; g++) {
        float4 v = *(const float4*)&sh[g * H2 + k0];
        c2[g] += v.x * w0 + v.y * w1 + v.z * w2 + v.w * w3;
      }
    }
#pragma unroll
    for (int g = 0; g < 64; g++) out[g * H + t] = gelu_f(c2[g]);
  }
}

// ---------------- host launch ----------------

extern "C" void kernel_launch(void* const* d_in, const int* in_sizes, int n_in,
                              void* d_out, int out_size, void* d_ws, size_t ws_size,
                              hipStream_t stream) {
  const float* x_in   = (const float*)d_in[0];
  const int*   edge   = (const int*)d_in[1];
  const int*   batch  = (const int*)d_in[2];
  const float* pre_W1 = (const float*)d_in[3];
  const float* pre_b1 = (const float*)d_in[4];
  const float* pre_W2 = (const float*)d_in[5];
  const float* pre_b2 = (const float*)d_in[6];
  const float* conv_W = (const float*)d_in[7];
  const float* conv_b = (const float*)d_in[8];
  const float* bn_g   = (const float*)d_in[9];
  const float* bn_b   = (const float*)d_in[10];
  const float* ffn_W1 = (const float*)d_in[11];
  const float* ffn_b1 = (const float*)d_in[12];
  const float* ffn_W2 = (const float*)d_in[13];
  const float* ffn_b2 = (const float*)d_in[14];
  const float* vn_W1  = (const float*)d_in[15];
  const float* vn_b1  = (const float*)d_in[16];
  const float* vn_g1  = (const float*)d_in[17];
  const float* vn_be1 = (const float*)d_in[18];
  const float* vn_W2  = (const float*)d_in[19];
  const float* vn_b2  = (const float*)d_in[20];
  const float* vn_g2  = (const float*)d_in[21];
  const float* vn_be2 = (const float*)d_in[22];
  const float* vn_emb = (const float*)d_in[23];
  const float* post_W1= (const float*)d_in[24];
  const float* post_b1= (const float*)d_in[25];
  const float* post_W2= (const float*)d_in[26];
  const float* post_b2= (const float*)d_in[27];
  float* out = (float*)d_out;

  const int N    = in_sizes[2];
  const int E    = in_sizes[1] / 2;
  const int G    = out_size / H;
  const int HOPS = in_sizes[7] / (H * H);
  const int NH   = N * H;

  // workspace layout
  float* w = (float*)d_ws;
  float* buf_x  = w;  w += NH;        // persistent node features
  float* buf_t  = w;  w += N * H2;    // FFN hidden; during GCN first NH = h
  float* buf_h  = buf_t;
  float* dinv   = w;  w += N;
  float* counts = w;  w += G;
  float* stats  = w;  w += 2 * H;
  float* scsh   = w;  w += 2 * H;
  float* pooled = w;  w += G * H;
  float* vn     = w;  w += G * H;
  float* csr_norm = w; w += E;
  int* iw = (int*)w;
  int* cnt     = iw;  iw += N;
  int* row_ptr = iw;  iw += N + 1;
  int* cursor  = iw;  iw += N;
  int* csr_src = iw;  iw += E;
  unsigned short* wt = (unsigned short*)iw;
  unsigned short* preW1T = wt;  wt += H * H2;
  unsigned short* preW2T = wt;  wt += H2 * H;
  unsigned short* convT  = wt;  wt += HOPS * H * H;
  unsigned short* ffn1T  = wt;  wt += HOPS * H * H2;
  unsigned short* ffn2T  = wt;  wt += HOPS * H2 * H;

  const int* src = edge;
  const int* dst = edge + E;

  int gN  = (N + 255) / 256;
  int gE  = (E + 255) / 256;
  int gM  = (N + 63) / 64;

  // weight transposes
  transpose_w<<<(H * H2 + 255) / 256, 256, 0, stream>>>(pre_W1, preW1T, H, H2, H * H2);
  transpose_w<<<(H2 * H + 255) / 256, 256, 0, stream>>>(pre_W2, preW2T, H2, H, H2 * H);
  transpose_w<<<(HOPS * H * H + 255) / 256, 256, 0, stream>>>(conv_W, convT, H, H, HOPS * H * H);
  transpose_w<<<(HOPS * H * H2 + 255) / 256, 256, 0, stream>>>(ffn_W1, ffn1T, H, H2, HOPS * H * H2);
  transpose_w<<<(HOPS * H2 * H + 255) / 256, 256, 0, stream>>>(ffn_W2, ffn2T, H2, H, HOPS * H2 * H);

  // CSR build + dinv
  hipMemsetAsync(cnt, 0, N * sizeof(int), stream);
  hist_kernel<<<gE, 256, 0, stream>>>(cnt, dst, E);
  dinv_kernel<<<gN, 256, 0, stream>>>(dinv, cnt, N);
  scan_kernel<<<1, 1024, 0, stream>>>(cnt, row_ptr, N, E);
  hipMemsetAsync(cursor, 0, N * sizeof(int), stream);
  build_csr_kernel<<<gE, 256, 0, stream>>>(src, dst, row_ptr, cursor, dinv, csr_src, csr_norm, E);

  // graph counts, vn init
  hipMemsetAsync(counts, 0, G * sizeof(float), stream);
  count_kernel<<<(N + 256 * 16 - 1) / (256 * 16), 256, 0, stream>>>(counts, batch, N, G);
  vn_init_kernel<<<(G * H + 255) / 256, 256, 0, stream>>>(vn, vn_emb, G * H);

  // pre-FFNN
  gemm_mfma<256, 1, 0, 1, 0, 0><<<gM, 256, 0, stream>>>(x_in, preW1T, pre_b1, nullptr, nullptr, nullptr, nullptr, nullptr, buf_t, N, H, H2);
  gemm_mfma<128, 1, 0, 1, 0, 0><<<gM, 256, 0, stream>>>(buf_t, preW2T, pre_b2, nullptr, nullptr, nullptr, nullptr, nullptr, buf_x, N, H2, H);

  for (int i = 0; i < HOPS; i++) {
    // GCN: h = (x + vn[batch]) @ W   (vn add fused into A-staging)
    gemm_mfma<128, 0, 0, 0, 0, 1><<<gM, 256, 0, stream>>>(buf_x, convT + i * H * H, nullptr, nullptr, nullptr, nullptr, vn, batch, buf_h, N, H, H);
    // x = x + vn[batch] + bias + selfloop + gathered edges
    gather_agg<<<(N + 3) / 4, 256, 0, stream>>>(buf_h, csr_src, csr_norm, row_ptr, dinv, vn, batch, conv_b + i * H, buf_x, N);
    // BN stats (apply fused into FFN GEMMs)
    hipMemsetAsync(stats, 0, 2 * H * sizeof(float), stream);
    bn_reduce_kernel<<<(N + 127) / 128, 256, 0, stream>>>(buf_x, stats, N);
    bn_finalize_kernel<<<1, 128, 0, stream>>>(stats, bn_g + i * H, bn_b + i * H, scsh, 1.0f / (float)N);
    // FFN: t = gelu(bn(x) @ W1 + b1); x = gelu(t @ W2 + b2) + bn(x)
    gemm_mfma<256, 1, 0, 1, 1, 0><<<gM, 256, 0, stream>>>(buf_x, ffn1T + i * H * H2, ffn_b1 + i * H2, scsh, nullptr, nullptr, nullptr, nullptr, buf_t, N, H, H2);
    gemm_mfma<128, 1, 2, 1, 0, 0><<<gM, 256, 0, stream>>>(buf_t, ffn2T + i * H2 * H, ffn_b2 + i * H, nullptr, scsh, buf_x, nullptr, nullptr, buf_x, N, H2, H);
    // virtual node update
    if (i < HOPS - 1) {
      hipMemsetAsync(pooled, 0, G * H * sizeof(float), stream);
      pool_kernel<<<(N + 127) / 128, 256, 0, stream>>>(pooled, buf_x, batch, N);
      vn_mlp_kernel<<<1, 256, 0, stream>>>(vn, pooled, counts,
                                           vn_W1 + i * H * H2, vn_b1 + i * H2, vn_g1 + i * H2, vn_be1 + i * H2,
                                           vn_W2 + i * H2 * H, vn_b2 + i * H, vn_g2 + i * H, vn_be2 + i * H);
    }
  }

  // final global_add_pool + post-FFNN
  hipMemsetAsync(pooled, 0, G * H * sizeof(float), stream);
  pool_kernel<<<(N + 127) / 128, 256, 0, stream>>>(pooled, buf_x, batch, N);
  post_kernel<<<1, 256, 0, stream>>>(out, pooled, post_W1, post_b1, post_W2, post_b2);
}

// Round 4
// 2555.944 us; speedup vs baseline: 2.3007x; 1.2403x over previous
//
#include <hip/hip_runtime.h>
#include <math.h>

#define H 128
#define H2 256
#define LDK 72  // LDS row stride in bf16 elements (144 B, 16B-aligned)

typedef __attribute__((ext_vector_type(8))) short short8;
typedef __attribute__((ext_vector_type(4))) float floatx4;

__device__ __forceinline__ float gelu_f(float x) {
  return 0.5f * x * (1.0f + erff(x * 0.70710678118654752440f));
}

__device__ __forceinline__ unsigned short f2b(float f) {
  union { float f; unsigned u; } c; c.f = f;
  unsigned r = c.u + 0x7fffu + ((c.u >> 16) & 1u);
  return (unsigned short)(r >> 16);
}

// ---------------- weight transpose+convert: W[b][K][N] fp32 -> WT[b][N][K] bf16 ----------------
__global__ __launch_bounds__(256) void transpose_w(const float* __restrict__ W, unsigned short* __restrict__ WT,
                                                   int K, int Ncol, int total) {
  int i = blockIdx.x * 256 + threadIdx.x;
  if (i >= total) return;
  int kn = K * Ncol;
  int b = i / kn, r = i - b * kn;
  int k = r / Ncol, n = r - k * Ncol;
  WT[b * kn + n * K + k] = f2b(W[i]);
}

// ---------------- CSR build ----------------

__global__ __launch_bounds__(256) void hist_kernel(int* __restrict__ cnt, const int* __restrict__ dst, int E) {
  int i = blockIdx.x * 256 + threadIdx.x;
  if (i < E) atomicAdd(&cnt[dst[i]], 1);
}

__global__ __launch_bounds__(256) void dinv_kernel(float* __restrict__ dinv, const int* __restrict__ cnt, int N) {
  int i = blockIdx.x * 256 + threadIdx.x;
  if (i < N) dinv[i] = rsqrtf((float)cnt[i] + 1.0f);  // +1 self loop
}

// single-block exclusive scan of cnt[0..N) -> row_ptr, row_ptr[N]=E
__global__ __launch_bounds__(1024) void scan_kernel(const int* __restrict__ cnt, int* __restrict__ row_ptr,
                                                    int N, int E) {
  __shared__ int part[1024];
  int t = threadIdx.x;
  int per = (N + 1023) / 1024;
  int beg = t * per;
  int end = beg + per; if (end > N) end = N;
  int s = 0;
  for (int i = beg; i < end; i++) s += cnt[i];
  part[t] = s;
  __syncthreads();
  for (int off = 1; off < 1024; off <<= 1) {
    int v = (t >= off) ? part[t - off] : 0;
    __syncthreads();
    part[t] += v;
    __syncthreads();
  }
  int prefix = (t == 0) ? 0 : part[t - 1];
  for (int i = beg; i < end; i++) {
    row_ptr[i] = prefix;
    prefix += cnt[i];
  }
  if (t == 1023) row_ptr[N] = E;
}

__global__ __launch_bounds__(256) void build_csr_kernel(const int* __restrict__ src, const int* __restrict__ dst,
                                                        const int* __restrict__ row_ptr, int* __restrict__ cursor,
                                                        const float* __restrict__ dinv,
                                                        int* __restrict__ csr_src, float* __restrict__ csr_norm,
                                                        int E) {
  int i = blockIdx.x * 256 + threadIdx.x;
  if (i < E) {
    int s = src[i], d = dst[i];
    int pos = row_ptr[d] + atomicAdd(&cursor[d], 1);
    csr_src[pos] = s;
    csr_norm[pos] = dinv[s] * dinv[d];
  }
}

// ---------------- small setup kernels ----------------

__global__ __launch_bounds__(256) void count_kernel(float* counts, const int* __restrict__ batch, int N, int G) {
  __shared__ float hist[256];
  int t = threadIdx.x;
  if (t < G) hist[t] = 0.f;
  __syncthreads();
  int i0 = (blockIdx.x * 256 + t) * 16;
  int cur = -1; float run = 0.f;
  for (int j = 0; j < 16; j++) {
    int i = i0 + j;
    if (i < N) {
      int b = batch[i];
      if (b == cur) run += 1.f;
      else { if (cur >= 0) atomicAdd(&hist[cur], run); cur = b; run = 1.f; }
    }
  }
  if (cur >= 0) atomicAdd(&hist[cur], run);
  __syncthreads();
  if (t < G && hist[t] != 0.f) atomicAdd(&counts[t], hist[t]);
}

__global__ __launch_bounds__(256) void vn_init_kernel(float* vn, const float* __restrict__ emb, int n) {
  int i = blockIdx.x * 256 + threadIdx.x;
  if (i < n) vn[i] = emb[i & (H - 1)];
}

// ---------------- fused gather aggregation ----------------
__global__ __launch_bounds__(256) void gather_agg(const float* __restrict__ h, const int* __restrict__ csr_src,
                                                  const float* __restrict__ csr_norm, const int* __restrict__ row_ptr,
                                                  const float* __restrict__ dinv, const float* __restrict__ vn,
                                                  const int* __restrict__ batch, const float* __restrict__ bias,
                                                  float* __restrict__ x, int N) {
  int node = blockIdx.x * 4 + (threadIdx.x >> 6);
  if (node >= N) return;
  int lane = threadIdx.x & 63;
  int c = lane * 2;
  float di = dinv[node];
  float2 hv = *(const float2*)&h[(long)node * H + c];
  float ax = hv.x * di * di, ay = hv.y * di * di;
  int beg = row_ptr[node], end = row_ptr[node + 1];
  for (int e = beg; e < end; e++) {
    int s = csr_src[e];
    float wgt = csr_norm[e];
    float2 v = *(const float2*)&h[(long)s * H + c];
    ax += v.x * wgt; ay += v.y * wgt;
  }
  int b = batch[node];
  float2 xo = *(const float2*)&x[(long)node * H + c];
  float2 vv = *(const float2*)&vn[b * H + c];
  float2 bi = *(const float2*)&bias[c];
  float2 r;
  r.x = ax + xo.x + vv.x + bi.x;
  r.y = ay + xo.y + vv.y + bi.y;
  *(float2*)&x[(long)node * H + c] = r;
}

// ---------------- BN stats ----------------

__global__ __launch_bounds__(256) void bn_reduce_kernel(const float* __restrict__ x, float* __restrict__ stats, int N) {
  __shared__ float ls[256], ls2[256];
  int t = threadIdx.x;
  int c = t & (H - 1);
  int r0 = blockIdx.x * 128 + (t >> 7);
  float s = 0.f, s2 = 0.f;
  for (int k = 0; k < 64; k++) {
    int r = r0 + k * 2;
    if (r < N) { float v = x[r * H + c]; s += v; s2 += v * v; }
  }
  ls[t] = s; ls2[t] = s2;
  __syncthreads();
  if (t < 128) {
    atomicAdd(&stats[c], ls[t] + ls[t + 128]);
    atomicAdd(&stats[H + c], ls2[t] + ls2[t + 128]);
  }
}

__global__ __launch_bounds__(128) void bn_finalize_kernel(const float* __restrict__ stats, const float* __restrict__ g,
                                                          const float* __restrict__ b, float* __restrict__ scsh,
                                                          float invN) {
  int c = threadIdx.x;
  float m = stats[c] * invN;
  float v = stats[H + c] * invN - m * m;
  float sc = rsqrtf(v + 1e-5f) * g[c];
  scsh[c] = sc;
  scsh[H + c] = b[c] - m * sc;
}

// ---------------- pooling (run-length over sorted batch) ----------------
__global__ __launch_bounds__(256) void pool_kernel(float* __restrict__ pooled, const float* __restrict__ x,
                                                   const int* __restrict__ batch, int N) {
  int c = threadIdx.x & 127;
  int slab = threadIdx.x >> 7;
  int r0 = blockIdx.x * 128 + slab;
  float acc = 0.f;
  int cur = -1;
  for (int k = 0; k < 64; k++) {
    int r = r0 + k * 2;
    if (r >= N) break;
    int b = batch[r];
    if (b != cur) {
      if (cur >= 0) atomicAdd(&pooled[cur * H + c], acc);
      cur = b; acc = 0.f;
    }
    acc += x[(long)r * H + c];
  }
  if (cur >= 0) atomicAdd(&pooled[cur * H + c], acc);
}

// ---------------- bf16 MFMA GEMM ----------------
template <int NT, int ACT, int RES, int HASBIAS, int ASCALE, int AVN>
__global__ __launch_bounds__(256) void gemm_mfma(const float* __restrict__ A,
                                                 const unsigned short* __restrict__ BT,
                                                 const float* __restrict__ bias,
                                                 const float* __restrict__ scshA,
                                                 const float* __restrict__ scshR,
                                                 const float* __restrict__ resid,
                                                 const float* __restrict__ vn,
                                                 const int* __restrict__ batch,
                                                 float* __restrict__ C, int M, int K, int Ncol) {
  __shared__ unsigned short As[64 * LDK];
  __shared__ unsigned short Bs[NT * LDK];
  int tid = threadIdx.x;
  int lane = tid & 63, w = tid >> 6;
  int row0 = blockIdx.x * 64;

  floatx4 acc[NT / 16];
#pragma unroll
  for (int t = 0; t < NT / 16; t++) acc[t] = (floatx4)0.f;

  int ar = tid >> 4;
  int ac4 = (tid & 15) * 4;
  int bn = tid >> 3;
  int bk8 = (tid & 7) * 8;

  int mrow = lane & 15;
  int quad = lane >> 4;

  for (int k0 = 0; k0 < K; k0 += 64) {
#pragma unroll
    for (int j = 0; j < 4; j++) {
      int r = j * 16 + ar;
      int gr = row0 + r;
      floatx4 v;
      if (gr < M) v = *(const floatx4*)&A[(long)gr * K + k0 + ac4];
      else v = (floatx4)0.f;
      if (ASCALE) {
        floatx4 sc = *(const floatx4*)&scshA[k0 + ac4];
        floatx4 sh = *(const floatx4*)&scshA[K + k0 + ac4];
        v = v * sc + sh;
      }
      if (AVN) {
        if (gr < M) {
          int b = batch[gr];
          floatx4 vv = *(const floatx4*)&vn[b * H + k0 + ac4];
          v = v + vv;
        }
      }
      unsigned long long p = (unsigned long long)f2b(v.x)
                           | ((unsigned long long)f2b(v.y) << 16)
                           | ((unsigned long long)f2b(v.z) << 32)
                           | ((unsigned long long)f2b(v.w) << 48);
      *(unsigned long long*)&As[r * LDK + ac4] = p;
    }
#pragma unroll
    for (int j = 0; j < NT / 32; j++) {
      int n = j * 32 + bn;
      short8 v = *(const short8*)&BT[(long)n * K + k0 + bk8];
      *(short8*)&Bs[n * LDK + bk8] = v;
    }
    __syncthreads();
#pragma unroll
    for (int kk = 0; kk < 2; kk++) {
      int kb = kk * 32 + quad * 8;
      short8 af = *(const short8*)&As[(w * 16 + mrow) * LDK + kb];
#pragma unroll
      for (int t = 0; t < NT / 16; t++) {
        short8 bf = *(const short8*)&Bs[(t * 16 + mrow) * LDK + kb];
        acc[t] = __builtin_amdgcn_mfma_f32_16x16x32_bf16(af, bf, acc[t], 0, 0, 0);
      }
    }
    __syncthreads();
  }

  int cn = lane & 15;
#pragma unroll
  for (int t = 0; t < NT / 16; t++) {
    int c = t * 16 + cn;
    float b = HASBIAS ? bias[c] : 0.f;
    float rsc = 0.f, rsh = 0.f;
    if (RES == 2) { rsc = scshR[c]; rsh = scshR[H + c]; }
#pragma unroll
    for (int i = 0; i < 4; i++) {
      int r = row0 + w * 16 + quad * 4 + i;
      if (r < M) {
        float v = acc[t][i] + b;
        if (ACT) v = gelu_f(v);
        long off = (long)r * Ncol + c;
        if (RES == 1) v += C[off];
        if (RES == 2) v += resid[off] * rsc + rsh;
        C[off] = v;
      }
    }
  }
}

// ---------------- parallel 64-row MLP stages ----------------
// Stage 1: h1[64][H2] = gelu( opt_bn( u @ W1 + b1 ) ); u[64][H]
//   UVN: u = vn + pooled / counts ; else u = pooled.
// grid: H2/64 = 4 blocks x 256 threads; block covers 64 columns.
template <int BN, int UVN>
__global__ __launch_bounds__(256) void mlp64_l1(const float* __restrict__ vn, const float* __restrict__ pooled,
                                                const float* __restrict__ counts,
                                                const float* __restrict__ W1, const float* __restrict__ b1,
                                                const float* __restrict__ g1, const float* __restrict__ be1,
                                                float* __restrict__ h1) {
  __shared__ float u[64 * H];     // 32 KB
  __shared__ float red[8 * 64];   // 2 KB: [0..3]=sum per tg, [4..7]=sumsq per tg
  int t = threadIdx.x;
  for (int idx = t; idx < 64 * H; idx += 256) {
    float v = pooled[idx];
    if (UVN) v = vn[idx] + v / fmaxf(counts[idx >> 7], 1.0f);
    u[idx] = v;
  }
  __syncthreads();
  int tc = t & 63, tg = t >> 6;
  int c = blockIdx.x * 64 + tc;
  float acc[16];
  float bj = b1[c];
#pragma unroll
  for (int g = 0; g < 16; g++) acc[g] = bj;
  for (int k0 = 0; k0 < H; k0 += 4) {
    float w0 = W1[(k0 + 0) * H2 + c];
    float w1 = W1[(k0 + 1) * H2 + c];
    float w2 = W1[(k0 + 2) * H2 + c];
    float w3 = W1[(k0 + 3) * H2 + c];
#pragma unroll
    for (int g = 0; g < 16; g++) {
      float4 v = *(const float4*)&u[(tg * 16 + g) * H + k0];
      acc[g] += v.x * w0 + v.y * w1 + v.z * w2 + v.w * w3;
    }
  }
  float sc = 1.f, sh = 0.f;
  if (BN) {
    float s = 0.f, s2 = 0.f;
#pragma unroll
    for (int g = 0; g < 16; g++) { s += acc[g]; s2 += acc[g] * acc[g]; }
    red[tg * 64 + tc] = s;
    red[256 + tg * 64 + tc] = s2;
    __syncthreads();
    float st = red[tc] + red[64 + tc] + red[128 + tc] + red[192 + tc];
    float st2 = red[256 + tc] + red[320 + tc] + red[384 + tc] + red[448 + tc];
    float m = st * (1.f / 64.f);
    float var = st2 * (1.f / 64.f) - m * m;
    sc = rsqrtf(var + 1e-5f) * g1[c];
    sh = be1[c] - m * sc;
  }
#pragma unroll
  for (int g = 0; g < 16; g++) h1[(tg * 16 + g) * H2 + c] = gelu_f(acc[g] * sc + sh);
}

// Stage 2: outp[64][H] = gelu( opt_bn( h1 @ W2 + b2 ) )
// grid: H/64 = 2 blocks x 256 threads. h1 read straight from L2 (wave-uniform float4).
template <int BN>
__global__ __launch_bounds__(256) void mlp64_l2(const float* __restrict__ h1,
                                                const float* __restrict__ W2, const float* __restrict__ b2,
                                                const float* __restrict__ g2, const float* __restrict__ be2,
                                                float* __restrict__ outp) {
  __shared__ float red[8 * 64];
  int t = threadIdx.x;
  int tc = t & 63, tg = t >> 6;
  int c = blockIdx.x * 64 + tc;
  float acc[16];
  float bj = b2[c];
#pragma unroll
  for (int g = 0; g < 16; g++) acc[g] = bj;
  for (int k0 = 0; k0 < H2; k0 += 4) {
    float w0 = W2[(k0 + 0) * H + c];
    float w1 = W2[(k0 + 1) * H + c];
    float w2 = W2[(k0 + 2) * H + c];
    float w3 = W2[(k0 + 3) * H + c];
#pragma unroll
    for (int g = 0; g < 16; g++) {
      float4 v = *(const float4*)&h1[(tg * 16 + g) * H2 + k0];
      acc[g] += v.x * w0 + v.y * w1 + v.z * w2 + v.w * w3;
    }
  }
  float sc = 1.f, sh = 0.f;
  if (BN) {
    float s = 0.f, s2 = 0.f;
#pragma unroll
    for (int g = 0; g < 16; g++) { s += acc[g]; s2 += acc[g] * acc[g]; }
    red[tg * 64 + tc] = s;
    red[256 + tg * 64 + tc] = s2;
    __syncthreads();
    float st = red[tc] + red[64 + tc] + red[128 + tc] + red[192 + tc];
    float st2 = red[256 + tc] + red[320 + tc] + red[384 + tc] + red[448 + tc];
    float m = st * (1.f / 64.f);
    float var = st2 * (1.f / 64.f) - m * m;
    sc = rsqrtf(var + 1e-5f) * g2[c];
    sh = be2[c] - m * sc;
  }
#pragma unroll
  for (int g = 0; g < 16; g++) outp[(tg * 16 + g) * H + c] = gelu_f(acc[g] * sc + sh);
}

// ---------------- host launch ----------------

extern "C" void kernel_launch(void* const* d_in, const int* in_sizes, int n_in,
                              void* d_out, int out_size, void* d_ws, size_t ws_size,
                              hipStream_t stream) {
  const float* x_in   = (const float*)d_in[0];
  const int*   edge   = (const int*)d_in[1];
  const int*   batch  = (const int*)d_in[2];
  const float* pre_W1 = (const float*)d_in[3];
  const float* pre_b1 = (const float*)d_in[4];
  const float* pre_W2 = (const float*)d_in[5];
  const float* pre_b2 = (const float*)d_in[6];
  const float* conv_W = (const float*)d_in[7];
  const float* conv_b = (const float*)d_in[8];
  const float* bn_g   = (const float*)d_in[9];
  const float* bn_b   = (const float*)d_in[10];
  const float* ffn_W1 = (const float*)d_in[11];
  const float* ffn_b1 = (const float*)d_in[12];
  const float* ffn_W2 = (const float*)d_in[13];
  const float* ffn_b2 = (const float*)d_in[14];
  const float* vn_W1  = (const float*)d_in[15];
  const float* vn_b1  = (const float*)d_in[16];
  const float* vn_g1  = (const float*)d_in[17];
  const float* vn_be1 = (const float*)d_in[18];
  const float* vn_W2  = (const float*)d_in[19];
  const float* vn_b2  = (const float*)d_in[20];
  const float* vn_g2  = (const float*)d_in[21];
  const float* vn_be2 = (const float*)d_in[22];
  const float* vn_emb = (const float*)d_in[23];
  const float* post_W1= (const float*)d_in[24];
  const float* post_b1= (const float*)d_in[25];
  const float* post_W2= (const float*)d_in[26];
  const float* post_b2= (const float*)d_in[27];
  float* out = (float*)d_out;

  const int N    = in_sizes[2];
  const int E    = in_sizes[1] / 2;
  const int G    = out_size / H;
  const int HOPS = in_sizes[7] / (H * H);
  const int NH   = N * H;

  // workspace layout
  float* w = (float*)d_ws;
  float* buf_x  = w;  w += NH;
  float* buf_t  = w;  w += N * H2;
  float* buf_h  = buf_t;
  float* dinv   = w;  w += N;
  float* counts = w;  w += G;
  float* stats  = w;  w += 2 * H;
  float* scsh   = w;  w += 2 * H;
  float* pooled = w;  w += G * H;
  float* vn     = w;  w += G * H;
  float* mlp_h1 = w;  w += G * H2;
  float* csr_norm = w; w += E;
  int* iw = (int*)w;
  int* cnt     = iw;  iw += N;
  int* row_ptr = iw;  iw += N + 1;
  int* cursor  = iw;  iw += N;
  int* csr_src = iw;  iw += E;
  unsigned short* wt = (unsigned short*)iw;
  unsigned short* preW1T = wt;  wt += H * H2;
  unsigned short* preW2T = wt;  wt += H2 * H;
  unsigned short* convT  = wt;  wt += HOPS * H * H;
  unsigned short* ffn1T  = wt;  wt += HOPS * H * H2;
  unsigned short* ffn2T  = wt;  wt += HOPS * H2 * H;

  const int* src = edge;
  const int* dst = edge + E;

  int gN  = (N + 255) / 256;
  int gE  = (E + 255) / 256;
  int gM  = (N + 63) / 64;

  // weight transposes
  transpose_w<<<(H * H2 + 255) / 256, 256, 0, stream>>>(pre_W1, preW1T, H, H2, H * H2);
  transpose_w<<<(H2 * H + 255) / 256, 256, 0, stream>>>(pre_W2, preW2T, H2, H, H2 * H);
  transpose_w<<<(HOPS * H * H + 255) / 256, 256, 0, stream>>>(conv_W, convT, H, H, HOPS * H * H);
  transpose_w<<<(HOPS * H * H2 + 255) / 256, 256, 0, stream>>>(ffn_W1, ffn1T, H, H2, HOPS * H * H2);
  transpose_w<<<(HOPS * H2 * H + 255) / 256, 256, 0, stream>>>(ffn_W2, ffn2T, H2, H, HOPS * H2 * H);

  // CSR build + dinv
  hipMemsetAsync(cnt, 0, N * sizeof(int), stream);
  hist_kernel<<<gE, 256, 0, stream>>>(cnt, dst, E);
  dinv_kernel<<<gN, 256, 0, stream>>>(dinv, cnt, N);
  scan_kernel<<<1, 1024, 0, stream>>>(cnt, row_ptr, N, E);
  hipMemsetAsync(cursor, 0, N * sizeof(int), stream);
  build_csr_kernel<<<gE, 256, 0, stream>>>(src, dst, row_ptr, cursor, dinv, csr_src, csr_norm, E);

  // graph counts, vn init
  hipMemsetAsync(counts, 0, G * sizeof(float), stream);
  count_kernel<<<(N + 256 * 16 - 1) / (256 * 16), 256, 0, stream>>>(counts, batch, N, G);
  vn_init_kernel<<<(G * H + 255) / 256, 256, 0, stream>>>(vn, vn_emb, G * H);

  // pre-FFNN
  gemm_mfma<256, 1, 0, 1, 0, 0><<<gM, 256, 0, stream>>>(x_in, preW1T, pre_b1, nullptr, nullptr, nullptr, nullptr, nullptr, buf_t, N, H, H2);
  gemm_mfma<128, 1, 0, 1, 0, 0><<<gM, 256, 0, stream>>>(buf_t, preW2T, pre_b2, nullptr, nullptr, nullptr, nullptr, nullptr, buf_x, N, H2, H);

  for (int i = 0; i < HOPS; i++) {
    // GCN: h = (x + vn[batch]) @ W   (vn add fused into A-staging)
    gemm_mfma<128, 0, 0, 0, 0, 1><<<gM, 256, 0, stream>>>(buf_x, convT + i * H * H, nullptr, nullptr, nullptr, nullptr, vn, batch, buf_h, N, H, H);
    // x = x + vn[batch] + bias + selfloop + gathered edges
    gather_agg<<<(N + 3) / 4, 256, 0, stream>>>(buf_h, csr_src, csr_norm, row_ptr, dinv, vn, batch, conv_b + i * H, buf_x, N);
    // BN stats (apply fused into FFN GEMMs)
    hipMemsetAsync(stats, 0, 2 * H * sizeof(float), stream);
    bn_reduce_kernel<<<(N + 127) / 128, 256, 0, stream>>>(buf_x, stats, N);
    bn_finalize_kernel<<<1, 128, 0, stream>>>(stats, bn_g + i * H, bn_b + i * H, scsh, 1.0f / (float)N);
    // FFN: t = gelu(bn(x) @ W1 + b1); x = gelu(t @ W2 + b2) + bn(x)
    gemm_mfma<256, 1, 0, 1, 1, 0><<<gM, 256, 0, stream>>>(buf_x, ffn1T + i * H * H2, ffn_b1 + i * H2, scsh, nullptr, nullptr, nullptr, nullptr, buf_t, N, H, H2);
    gemm_mfma<128, 1, 2, 1, 0, 0><<<gM, 256, 0, stream>>>(buf_t, ffn2T + i * H2 * H, ffn_b2 + i * H, nullptr, scsh, buf_x, nullptr, nullptr, buf_x, N, H2, H);
    // virtual node update (multi-block MLP)
    if (i < HOPS - 1) {
      hipMemsetAsync(pooled, 0, G * H * sizeof(float), stream);
      pool_kernel<<<(N + 127) / 128, 256, 0, stream>>>(pooled, buf_x, batch, N);
      mlp64_l1<1, 1><<<H2 / 64, 256, 0, stream>>>(vn, pooled, counts,
                                                  vn_W1 + i * H * H2, vn_b1 + i * H2, vn_g1 + i * H2, vn_be1 + i * H2,
                                                  mlp_h1);
      mlp64_l2<1><<<H / 64, 256, 0, stream>>>(mlp_h1, vn_W2 + i * H2 * H, vn_b2 + i * H, vn_g2 + i * H, vn_be2 + i * H, vn);
    }
  }

  // final global_add_pool + post-FFNN (multi-block MLP)
  hipMemsetAsync(pooled, 0, G * H * sizeof(float), stream);
  pool_kernel<<<(N + 127) / 128, 256, 0, stream>>>(pooled, buf_x, batch, N);
  mlp64_l1<0, 0><<<H2 / 64, 256, 0, stream>>>(nullptr, pooled, nullptr, post_W1, post_b1, nullptr, nullptr, mlp_h1);
  mlp64_l2<0><<<H / 64, 256, 0, stream>>>(mlp_h1, post_W2, post_b2, nullptr, nullptr, out);
}

// Round 5
// 2253.727 us; speedup vs baseline: 2.6092x; 1.1341x over previous
//
#include <hip/hip_runtime.h>
#include <math.h>

#define H 128
#define H2 256
#define LDK 72  // LDS row stride in bf16 elements (144 B, 16B-aligned)

typedef __attribute__((ext_vector_type(8))) short short8;
typedef __attribute__((ext_vector_type(4))) float floatx4;

__device__ __forceinline__ float gelu_f(float x) {
  return 0.5f * x * (1.0f + erff(x * 0.70710678118654752440f));
}

__device__ __forceinline__ unsigned short f2b(float f) {
  union { float f; unsigned u; } c; c.f = f;
  unsigned r = c.u + 0x7fffu + ((c.u >> 16) & 1u);
  return (unsigned short)(r >> 16);
}

__device__ __forceinline__ float b2f(unsigned short u) {
  union { unsigned u; float f; } c; c.u = ((unsigned)u) << 16; return c.f;
}

// ---------------- weight transpose+convert: W[b][K][N] fp32 -> WT[b][N][K] bf16 ----------------
__global__ __launch_bounds__(256) void transpose_w(const float* __restrict__ W, unsigned short* __restrict__ WT,
                                                   int K, int Ncol, int total) {
  int i = blockIdx.x * 256 + threadIdx.x;
  if (i >= total) return;
  int kn = K * Ncol;
  int b = i / kn, r = i - b * kn;
  int k = r / Ncol, n = r - k * Ncol;
  WT[b * kn + n * K + k] = f2b(W[i]);
}

// ---------------- CSR build ----------------

__global__ __launch_bounds__(256) void hist_kernel(int* __restrict__ cnt, const int* __restrict__ dst, int E) {
  int i = blockIdx.x * 256 + threadIdx.x;
  if (i < E) atomicAdd(&cnt[dst[i]], 1);
}

// phase A: per-block (1024 elems) local exclusive scan + block sums; also dinv
__global__ __launch_bounds__(256) void scan_a(const int* __restrict__ cnt, int* __restrict__ row_ptr,
                                              int* __restrict__ blockSum, float* __restrict__ dinv, int N) {
  __shared__ int ls[256];
  int t = threadIdx.x;
  int idx = blockIdx.x * 1024 + t * 4;
  int4 v = make_int4(0, 0, 0, 0);
  if (idx + 3 < N) v = *(const int4*)&cnt[idx];
  else {
    if (idx + 0 < N) v.x = cnt[idx + 0];
    if (idx + 1 < N) v.y = cnt[idx + 1];
    if (idx + 2 < N) v.z = cnt[idx + 2];
    if (idx + 3 < N) v.w = cnt[idx + 3];
  }
  if (idx + 0 < N) dinv[idx + 0] = rsqrtf((float)v.x + 1.0f);
  if (idx + 1 < N) dinv[idx + 1] = rsqrtf((float)v.y + 1.0f);
  if (idx + 2 < N) dinv[idx + 2] = rsqrtf((float)v.z + 1.0f);
  if (idx + 3 < N) dinv[idx + 3] = rsqrtf((float)v.w + 1.0f);
  int s = v.x + v.y + v.z + v.w;
  ls[t] = s;
  __syncthreads();
  for (int off = 1; off < 256; off <<= 1) {
    int a = (t >= off) ? ls[t - off] : 0;
    __syncthreads();
    ls[t] += a;
    __syncthreads();
  }
  int p = ls[t] - s;  // exclusive prefix within block
  if (t == 255) blockSum[blockIdx.x] = ls[255];
  if (idx + 0 < N) row_ptr[idx + 0] = p;  p += v.x;
  if (idx + 1 < N) row_ptr[idx + 1] = p;  p += v.y;
  if (idx + 2 < N) row_ptr[idx + 2] = p;  p += v.z;
  if (idx + 3 < N) row_ptr[idx + 3] = p;
}

// phase B: single-block scan of block sums (nb <= 1024)
__global__ __launch_bounds__(1024) void scan_b(const int* __restrict__ blockSum, int* __restrict__ blockOff,
                                               int nb, int* __restrict__ row_ptr, int N, int E) {
  __shared__ int ls[1024];
  int t = threadIdx.x;
  int s = (t < nb) ? blockSum[t] : 0;
  ls[t] = s;
  __syncthreads();
  for (int off = 1; off < 1024; off <<= 1) {
    int a = (t >= off) ? ls[t - off] : 0;
    __syncthreads();
    ls[t] += a;
    __syncthreads();
  }
  if (t < nb) blockOff[t] = ls[t] - s;
  if (t == 0) row_ptr[N] = E;
}

// phase C: add block offsets
__global__ __launch_bounds__(256) void scan_c(int* __restrict__ row_ptr, const int* __restrict__ blockOff, int N) {
  int t = threadIdx.x;
  int idx = blockIdx.x * 1024 + t * 4;
  int off = blockOff[blockIdx.x];
  if (off == 0) return;
  if (idx + 3 < N) {
    int4 v = *(const int4*)&row_ptr[idx];
    v.x += off; v.y += off; v.z += off; v.w += off;
    *(int4*)&row_ptr[idx] = v;
  } else {
    if (idx + 0 < N) row_ptr[idx + 0] += off;
    if (idx + 1 < N) row_ptr[idx + 1] += off;
    if (idx + 2 < N) row_ptr[idx + 2] += off;
    if (idx + 3 < N) row_ptr[idx + 3] += off;
  }
}

__global__ __launch_bounds__(256) void build_csr_kernel(const int* __restrict__ src, const int* __restrict__ dst,
                                                        const int* __restrict__ row_ptr, int* __restrict__ cursor,
                                                        const float* __restrict__ dinv,
                                                        int* __restrict__ csr_src, float* __restrict__ csr_norm,
                                                        int E) {
  int i = blockIdx.x * 256 + threadIdx.x;
  if (i < E) {
    int s = src[i], d = dst[i];
    int pos = row_ptr[d] + atomicAdd(&cursor[d], 1);
    csr_src[pos] = s;
    csr_norm[pos] = dinv[s] * dinv[d];
  }
}

// ---------------- small setup kernels ----------------

__global__ __launch_bounds__(256) void count_kernel(float* counts, const int* __restrict__ batch, int N, int G) {
  __shared__ float hist[256];
  int t = threadIdx.x;
  if (t < G) hist[t] = 0.f;
  __syncthreads();
  int i0 = (blockIdx.x * 256 + t) * 16;
  int cur = -1; float run = 0.f;
  for (int j = 0; j < 16; j++) {
    int i = i0 + j;
    if (i < N) {
      int b = batch[i];
      if (b == cur) run += 1.f;
      else { if (cur >= 0) atomicAdd(&hist[cur], run); cur = b; run = 1.f; }
    }
  }
  if (cur >= 0) atomicAdd(&hist[cur], run);
  __syncthreads();
  if (t < G && hist[t] != 0.f) atomicAdd(&counts[t], hist[t]);
}

__global__ __launch_bounds__(256) void vn_init_kernel(float* vn, const float* __restrict__ emb, int n) {
  int i = blockIdx.x * 256 + threadIdx.x;
  if (i < n) vn[i] = emb[i & (H - 1)];
}

// ---------------- fused gather aggregation (bf16 h) ----------------
// x[node] = x[node] + vn[batch[node]] + bias + h[node]*dinv^2 + sum_edges h[src]*norm
// one wave per node, lane handles 2 cols (2 bf16 = 4 B)
__global__ __launch_bounds__(256) void gather_agg(const unsigned short* __restrict__ h, const int* __restrict__ csr_src,
                                                  const float* __restrict__ csr_norm, const int* __restrict__ row_ptr,
                                                  const float* __restrict__ dinv, const float* __restrict__ vn,
                                                  const int* __restrict__ batch, const float* __restrict__ bias,
                                                  float* __restrict__ x, int N) {
  int node = blockIdx.x * 4 + (threadIdx.x >> 6);
  if (node >= N) return;
  int lane = threadIdx.x & 63;
  int c = lane * 2;
  float di = dinv[node];
  unsigned hv = *(const unsigned*)&h[(long)node * H + c];
  float ax = b2f((unsigned short)hv) * di * di;
  float ay = b2f((unsigned short)(hv >> 16)) * di * di;
  int beg = row_ptr[node], end = row_ptr[node + 1];
  int e = beg;
  for (; e + 2 <= end; e += 2) {
    int s0 = csr_src[e], s1 = csr_src[e + 1];
    float w0 = csr_norm[e], w1 = csr_norm[e + 1];
    unsigned v0 = *(const unsigned*)&h[(long)s0 * H + c];
    unsigned v1 = *(const unsigned*)&h[(long)s1 * H + c];
    ax += b2f((unsigned short)v0) * w0 + b2f((unsigned short)v1) * w1;
    ay += b2f((unsigned short)(v0 >> 16)) * w0 + b2f((unsigned short)(v1 >> 16)) * w1;
  }
  if (e < end) {
    int s0 = csr_src[e];
    float w0 = csr_norm[e];
    unsigned v0 = *(const unsigned*)&h[(long)s0 * H + c];
    ax += b2f((unsigned short)v0) * w0;
    ay += b2f((unsigned short)(v0 >> 16)) * w0;
  }
  int b = batch[node];
  float2 xo = *(const float2*)&x[(long)node * H + c];
  float2 vv = *(const float2*)&vn[b * H + c];
  float2 bi = *(const float2*)&bias[c];
  float2 r;
  r.x = ax + xo.x + vv.x + bi.x;
  r.y = ay + xo.y + vv.y + bi.y;
  *(float2*)&x[(long)node * H + c] = r;
}

// ---------------- BN stats ----------------

__global__ __launch_bounds__(256) void bn_reduce_kernel(const float* __restrict__ x, float* __restrict__ stats, int N) {
  __shared__ float ls[256], ls2[256];
  int t = threadIdx.x;
  int c = t & (H - 1);
  int r0 = blockIdx.x * 128 + (t >> 7);
  float s = 0.f, s2 = 0.f;
  for (int k = 0; k < 64; k++) {
    int r = r0 + k * 2;
    if (r < N) { float v = x[r * H + c]; s += v; s2 += v * v; }
  }
  ls[t] = s; ls2[t] = s2;
  __syncthreads();
  if (t < 128) {
    atomicAdd(&stats[c], ls[t] + ls[t + 128]);
    atomicAdd(&stats[H + c], ls2[t] + ls2[t + 128]);
  }
}

__global__ __launch_bounds__(128) void bn_finalize_kernel(const float* __restrict__ stats, const float* __restrict__ g,
                                                          const float* __restrict__ b, float* __restrict__ scsh,
                                                          float invN) {
  int c = threadIdx.x;
  float m = stats[c] * invN;
  float v = stats[H + c] * invN - m * m;
  float sc = rsqrtf(v + 1e-5f) * g[c];
  scsh[c] = sc;
  scsh[H + c] = b[c] - m * sc;
}

// ---------------- pooling (run-length over sorted batch) ----------------
__global__ __launch_bounds__(256) void pool_kernel(float* __restrict__ pooled, const float* __restrict__ x,
                                                   const int* __restrict__ batch, int N) {
  int c = threadIdx.x & 127;
  int slab = threadIdx.x >> 7;
  int r0 = blockIdx.x * 128 + slab;
  float acc = 0.f;
  int cur = -1;
  for (int k = 0; k < 64; k++) {
    int r = r0 + k * 2;
    if (r >= N) break;
    int b = batch[r];
    if (b != cur) {
      if (cur >= 0) atomicAdd(&pooled[cur * H + c], acc);
      cur = b; acc = 0.f;
    }
    acc += x[(long)r * H + c];
  }
  if (cur >= 0) atomicAdd(&pooled[cur * H + c], acc);
}

// ---------------- bf16 MFMA GEMM ----------------
// OUT16: write bf16 output to C16 instead of fp32 to C.
template <int NT, int ACT, int RES, int HASBIAS, int ASCALE, int AVN, int OUT16>
__global__ __launch_bounds__(256) void gemm_mfma(const float* __restrict__ A,
                                                 const unsigned short* __restrict__ BT,
                                                 const float* __restrict__ bias,
                                                 const float* __restrict__ scshA,
                                                 const float* __restrict__ scshR,
                                                 const float* __restrict__ resid,
                                                 const float* __restrict__ vn,
                                                 const int* __restrict__ batch,
                                                 float* __restrict__ C, unsigned short* __restrict__ C16,
                                                 int M, int K, int Ncol) {
  __shared__ unsigned short As[64 * LDK];
  __shared__ unsigned short Bs[NT * LDK];
  int tid = threadIdx.x;
  int lane = tid & 63, w = tid >> 6;
  int row0 = blockIdx.x * 64;

  floatx4 acc[NT / 16];
#pragma unroll
  for (int t = 0; t < NT / 16; t++) acc[t] = (floatx4)0.f;

  int ar = tid >> 4;
  int ac4 = (tid & 15) * 4;
  int bn = tid >> 3;
  int bk8 = (tid & 7) * 8;

  int mrow = lane & 15;
  int quad = lane >> 4;

  for (int k0 = 0; k0 < K; k0 += 64) {
#pragma unroll
    for (int j = 0; j < 4; j++) {
      int r = j * 16 + ar;
      int gr = row0 + r;
      floatx4 v;
      if (gr < M) v = *(const floatx4*)&A[(long)gr * K + k0 + ac4];
      else v = (floatx4)0.f;
      if (ASCALE) {
        floatx4 sc = *(const floatx4*)&scshA[k0 + ac4];
        floatx4 sh = *(const floatx4*)&scshA[K + k0 + ac4];
        v = v * sc + sh;
      }
      if (AVN) {
        if (gr < M) {
          int b = batch[gr];
          floatx4 vv = *(const floatx4*)&vn[b * H + k0 + ac4];
          v = v + vv;
        }
      }
      unsigned long long p = (unsigned long long)f2b(v.x)
                           | ((unsigned long long)f2b(v.y) << 16)
                           | ((unsigned long long)f2b(v.z) << 32)
                           | ((unsigned long long)f2b(v.w) << 48);
      *(unsigned long long*)&As[r * LDK + ac4] = p;
    }
#pragma unroll
    for (int j = 0; j < NT / 32; j++) {
      int n = j * 32 + bn;
      short8 v = *(const short8*)&BT[(long)n * K + k0 + bk8];
      *(short8*)&Bs[n * LDK + bk8] = v;
    }
    __syncthreads();
#pragma unroll
    for (int kk = 0; kk < 2; kk++) {
      int kb = kk * 32 + quad * 8;
      short8 af = *(const short8*)&As[(w * 16 + mrow) * LDK + kb];
#pragma unroll
      for (int t = 0; t < NT / 16; t++) {
        short8 bf = *(const short8*)&Bs[(t * 16 + mrow) * LDK + kb];
        acc[t] = __builtin_amdgcn_mfma_f32_16x16x32_bf16(af, bf, acc[t], 0, 0, 0);
      }
    }
    __syncthreads();
  }

  int cn = lane & 15;
#pragma unroll
  for (int t = 0; t < NT / 16; t++) {
    int c = t * 16 + cn;
    float b = HASBIAS ? bias[c] : 0.f;
    float rsc = 0.f, rsh = 0.f;
    if (RES == 2) { rsc = scshR[c]; rsh = scshR[H + c]; }
#pragma unroll
    for (int i = 0; i < 4; i++) {
      int r = row0 + w * 16 + quad * 4 + i;
      if (r < M) {
        float v = acc[t][i] + b;
        if (ACT) v = gelu_f(v);
        long off = (long)r * Ncol + c;
        if (OUT16) {
          C16[off] = f2b(v);
        } else {
          if (RES == 1) v += C[off];
          if (RES == 2) v += resid[off] * rsc + rsh;
          C[off] = v;
        }
      }
    }
  }
}

// ---------------- parallel 64-row MLP stages ----------------
template <int BN, int UVN>
__global__ __launch_bounds__(256) void mlp64_l1(const float* __restrict__ vn, const float* __restrict__ pooled,
                                                const float* __restrict__ counts,
                                                const float* __restrict__ W1, const float* __restrict__ b1,
                                                const float* __restrict__ g1, const float* __restrict__ be1,
                                                float* __restrict__ h1) {
  __shared__ float u[64 * H];
  __shared__ float red[8 * 64];
  int t = threadIdx.x;
  for (int idx = t; idx < 64 * H; idx += 256) {
    float v = pooled[idx];
    if (UVN) v = vn[idx] + v / fmaxf(counts[idx >> 7], 1.0f);
    u[idx] = v;
  }
  __syncthreads();
  int tc = t & 63, tg = t >> 6;
  int c = blockIdx.x * 64 + tc;
  float acc[16];
  float bj = b1[c];
#pragma unroll
  for (int g = 0; g < 16; g++) acc[g] = bj;
  for (int k0 = 0; k0 < H; k0 += 4) {
    float w0 = W1[(k0 + 0) * H2 + c];
    float w1 = W1[(k0 + 1) * H2 + c];
    float w2 = W1[(k0 + 2) * H2 + c];
    float w3 = W1[(k0 + 3) * H2 + c];
#pragma unroll
    for (int g = 0; g < 16; g++) {
      float4 v = *(const float4*)&u[(tg * 16 + g) * H + k0];
      acc[g] += v.x * w0 + v.y * w1 + v.z * w2 + v.w * w3;
    }
  }
  float sc = 1.f, sh = 0.f;
  if (BN) {
    float s = 0.f, s2 = 0.f;
#pragma unroll
    for (int g = 0; g < 16; g++) { s += acc[g]; s2 += acc[g] * acc[g]; }
    red[tg * 64 + tc] = s;
    red[256 + tg * 64 + tc] = s2;
    __syncthreads();
    float st = red[tc] + red[64 + tc] + red[128 + tc] + red[192 + tc];
    float st2 = red[256 + tc] + red[320 + tc] + red[384 + tc] + red[448 + tc];
    float m = st * (1.f / 64.f);
    float var = st2 * (1.f / 64.f) - m * m;
    sc = rsqrtf(var + 1e-5f) * g1[c];
    sh = be1[c] - m * sc;
  }
#pragma unroll
  for (int g = 0; g < 16; g++) h1[(tg * 16 + g) * H2 + c] = gelu_f(acc[g] * sc + sh);
}

template <int BN>
__global__ __launch_bounds__(256) void mlp64_l2(const float* __restrict__ h1,
                                                const float* __restrict__ W2, const float* __restrict__ b2,
                                                const float* __restrict__ g2, const float* __restrict__ be2,
                                                float* __restrict__ outp) {
  __shared__ float red[8 * 64];
  int t = threadIdx.x;
  int tc = t & 63, tg = t >> 6;
  int c = blockIdx.x * 64 + tc;
  float acc[16];
  float bj = b2[c];
#pragma unroll
  for (int g = 0; g < 16; g++) acc[g] = bj;
  for (int k0 = 0; k0 < H2; k0 += 4) {
    float w0 = W2[(k0 + 0) * H + c];
    float w1 = W2[(k0 + 1) * H + c];
    float w2 = W2[(k0 + 2) * H + c];
    float w3 = W2[(k0 + 3) * H + c];
#pragma unroll
    for (int g = 0; g < 16; g++) {
      float4 v = *(const float4*)&h1[(tg * 16 + g) * H2 + k0];
      acc[g] += v.x * w0 + v.y * w1 + v.z * w2 + v.w * w3;
    }
  }
  float sc = 1.f, sh = 0.f;
  if (BN) {
    float s = 0.f, s2 = 0.f;
#pragma unroll
    for (int g = 0; g < 16; g++) { s += acc[g]; s2 += acc[g] * acc[g]; }
    red[tg * 64 + tc] = s;
    red[256 + tg * 64 + tc] = s2;
    __syncthreads();
    float st = red[tc] + red[64 + tc] + red[128 + tc] + red[192 + tc];
    float st2 = red[256 + tc] + red[320 + tc] + red[384 + tc] + red[448 + tc];
    float m = st * (1.f / 64.f);
    float var = st2 * (1.f / 64.f) - m * m;
    sc = rsqrtf(var + 1e-5f) * g2[c];
    sh = be2[c] - m * sc;
  }
#pragma unroll
  for (int g = 0; g < 16; g++) outp[(tg * 16 + g) * H + c] = gelu_f(acc[g] * sc + sh);
}

// ---------------- host launch ----------------

extern "C" void kernel_launch(void* const* d_in, const int* in_sizes, int n_in,
                              void* d_out, int out_size, void* d_ws, size_t ws_size,
                              hipStream_t stream) {
  const float* x_in   = (const float*)d_in[0];
  const int*   edge   = (const int*)d_in[1];
  const int*   batch  = (const int*)d_in[2];
  const float* pre_W1 = (const float*)d_in[3];
  const float* pre_b1 = (const float*)d_in[4];
  const float* pre_W2 = (const float*)d_in[5];
  const float* pre_b2 = (const float*)d_in[6];
  const float* conv_W = (const float*)d_in[7];
  const float* conv_b = (const float*)d_in[8];
  const float* bn_g   = (const float*)d_in[9];
  const float* bn_b   = (const float*)d_in[10];
  const float* ffn_W1 = (const float*)d_in[11];
  const float* ffn_b1 = (const float*)d_in[12];
  const float* ffn_W2 = (const float*)d_in[13];
  const float* ffn_b2 = (const float*)d_in[14];
  const float* vn_W1  = (const float*)d_in[15];
  const float* vn_b1  = (const float*)d_in[16];
  const float* vn_g1  = (const float*)d_in[17];
  const float* vn_be1 = (const float*)d_in[18];
  const float* vn_W2  = (const float*)d_in[19];
  const float* vn_b2  = (const float*)d_in[20];
  const float* vn_g2  = (const float*)d_in[21];
  const float* vn_be2 = (const float*)d_in[22];
  const float* vn_emb = (const float*)d_in[23];
  const float* post_W1= (const float*)d_in[24];
  const float* post_b1= (const float*)d_in[25];
  const float* post_W2= (const float*)d_in[26];
  const float* post_b2= (const float*)d_in[27];
  float* out = (float*)d_out;

  const int N    = in_sizes[2];
  const int E    = in_sizes[1] / 2;
  const int G    = out_size / H;
  const int HOPS = in_sizes[7] / (H * H);
  const int NH   = N * H;

  // workspace layout
  float* w = (float*)d_ws;
  float* buf_x  = w;  w += NH;
  float* buf_t  = w;  w += N * H2;
  unsigned short* buf_h16 = (unsigned short*)buf_t;  // conv output (bf16), overwritten later by FFN hidden
  float* dinv   = w;  w += N;
  float* counts = w;  w += G;
  float* stats  = w;  w += 2 * H;
  float* scsh   = w;  w += 2 * H;
  float* pooled = w;  w += G * H;
  float* vn     = w;  w += G * H;
  float* mlp_h1 = w;  w += G * H2;
  float* csr_norm = w; w += E;
  int* iw = (int*)w;
  int* cnt      = iw;  iw += N;
  int* row_ptr  = iw;  iw += N + 1;
  int* cursor   = iw;  iw += N;
  int* csr_src  = iw;  iw += E;
  int* blockSum = iw;  iw += 1024;
  int* blockOff = iw;  iw += 1024;
  unsigned short* wt = (unsigned short*)iw;
  unsigned short* preW1T = wt;  wt += H * H2;
  unsigned short* preW2T = wt;  wt += H2 * H;
  unsigned short* convT  = wt;  wt += HOPS * H * H;
  unsigned short* ffn1T  = wt;  wt += HOPS * H * H2;
  unsigned short* ffn2T  = wt;  wt += HOPS * H2 * H;

  const int* src = edge;
  const int* dst = edge + E;

  int gE  = (E + 255) / 256;
  int gM  = (N + 63) / 64;
  int nb  = (N + 1023) / 1024;  // scan blocks (<= 1024)

  // weight transposes
  transpose_w<<<(H * H2 + 255) / 256, 256, 0, stream>>>(pre_W1, preW1T, H, H2, H * H2);
  transpose_w<<<(H2 * H + 255) / 256, 256, 0, stream>>>(pre_W2, preW2T, H2, H, H2 * H);
  transpose_w<<<(HOPS * H * H + 255) / 256, 256, 0, stream>>>(conv_W, convT, H, H, HOPS * H * H);
  transpose_w<<<(HOPS * H * H2 + 255) / 256, 256, 0, stream>>>(ffn_W1, ffn1T, H, H2, HOPS * H * H2);
  transpose_w<<<(HOPS * H2 * H + 255) / 256, 256, 0, stream>>>(ffn_W2, ffn2T, H2, H, HOPS * H2 * H);

  // CSR build + dinv (parallel 3-phase scan; dinv fused into scan_a)
  hipMemsetAsync(cnt, 0, N * sizeof(int), stream);
  hist_kernel<<<gE, 256, 0, stream>>>(cnt, dst, E);
  scan_a<<<nb, 256, 0, stream>>>(cnt, row_ptr, blockSum, dinv, N);
  scan_b<<<1, 1024, 0, stream>>>(blockSum, blockOff, nb, row_ptr, N, E);
  scan_c<<<nb, 256, 0, stream>>>(row_ptr, blockOff, N);
  hipMemsetAsync(cursor, 0, N * sizeof(int), stream);
  build_csr_kernel<<<gE, 256, 0, stream>>>(src, dst, row_ptr, cursor, dinv, csr_src, csr_norm, E);

  // graph counts, vn init
  hipMemsetAsync(counts, 0, G * sizeof(float), stream);
  count_kernel<<<(N + 256 * 16 - 1) / (256 * 16), 256, 0, stream>>>(counts, batch, N, G);
  vn_init_kernel<<<(G * H + 255) / 256, 256, 0, stream>>>(vn, vn_emb, G * H);

  // pre-FFNN
  gemm_mfma<256, 1, 0, 1, 0, 0, 0><<<gM, 256, 0, stream>>>(x_in, preW1T, pre_b1, nullptr, nullptr, nullptr, nullptr, nullptr, buf_t, nullptr, N, H, H2);
  gemm_mfma<128, 1, 0, 1, 0, 0, 0><<<gM, 256, 0, stream>>>(buf_t, preW2T, pre_b2, nullptr, nullptr, nullptr, nullptr, nullptr, buf_x, nullptr, N, H2, H);

  for (int i = 0; i < HOPS; i++) {
    // GCN: h16 = bf16( (x + vn[batch]) @ W )
    gemm_mfma<128, 0, 0, 0, 0, 1, 1><<<gM, 256, 0, stream>>>(buf_x, convT + i * H * H, nullptr, nullptr, nullptr, nullptr, vn, batch, nullptr, buf_h16, N, H, H);
    // x = x + vn[batch] + bias + selfloop + gathered edges (bf16 h)
    gather_agg<<<(N + 3) / 4, 256, 0, stream>>>(buf_h16, csr_src, csr_norm, row_ptr, dinv, vn, batch, conv_b + i * H, buf_x, N);
    // BN stats (apply fused into FFN GEMMs)
    hipMemsetAsync(stats, 0, 2 * H * sizeof(float), stream);
    bn_reduce_kernel<<<(N + 127) / 128, 256, 0, stream>>>(buf_x, stats, N);
    bn_finalize_kernel<<<1, 128, 0, stream>>>(stats, bn_g + i * H, bn_b + i * H, scsh, 1.0f / (float)N);
    // FFN: t = gelu(bn(x) @ W1 + b1); x = gelu(t @ W2 + b2) + bn(x)
    gemm_mfma<256, 1, 0, 1, 1, 0, 0><<<gM, 256, 0, stream>>>(buf_x, ffn1T + i * H * H2, ffn_b1 + i * H2, scsh, nullptr, nullptr, nullptr, nullptr, buf_t, nullptr, N, H, H2);
    gemm_mfma<128, 1, 2, 1, 0, 0, 0><<<gM, 256, 0, stream>>>(buf_t, ffn2T + i * H2 * H, ffn_b2 + i * H, nullptr, scsh, buf_x, nullptr, nullptr, buf_x, nullptr, N, H2, H);
    // virtual node update (multi-block MLP)
    if (i < HOPS - 1) {
      hipMemsetAsync(pooled, 0, G * H * sizeof(float), stream);
      pool_kernel<<<(N + 127) / 128, 256, 0, stream>>>(pooled, buf_x, batch, N);
      mlp64_l1<1, 1><<<H2 / 64, 256, 0, stream>>>(vn, pooled, counts,
                                                  vn_W1 + i * H * H2, vn_b1 + i * H2, vn_g1 + i * H2, vn_be1 + i * H2,
                                                  mlp_h1);
      mlp64_l2<1><<<H / 64, 256, 0, stream>>>(mlp_h1, vn_W2 + i * H2 * H, vn_b2 + i * H, vn_g2 + i * H, vn_be2 + i * H, vn);
    }
  }

  // final global_add_pool + post-FFNN (multi-block MLP)
  hipMemsetAsync(pooled, 0, G * H * sizeof(float), stream);
  pool_kernel<<<(N + 127) / 128, 256, 0, stream>>>(pooled, buf_x, batch, N);
  mlp64_l1<0, 0><<<H2 / 64, 256, 0, stream>>>(nullptr, pooled, nullptr, post_W1, post_b1, nullptr, nullptr, mlp_h1);
  mlp64_l2<0><<<H / 64, 256, 0, stream>>>(mlp_h1, post_W2, post_b2, nullptr, nullptr, out);
}

// Round 7
// 2039.367 us; speedup vs baseline: 2.8835x; 1.1051x over previous
//
#include <hip/hip_runtime.h>
#include <math.h>

#define H 128
#define H2 256
#define LDK 72   // LDS row stride (bf16) for 64-wide k blocks
#define LDH 264  // LDS row stride (bf16) for the fused hidden (256 k)
// ffn_fused LDS: phase1 needs 64*LDK + H2*LDK = 23040 shorts;
// phase2 overlay needs 64*LDH + H*LDK = 26112 shorts. Take the max.
#define FFN_SMEM (64 * LDH + H * LDK)

typedef __attribute__((ext_vector_type(8))) short short8;
typedef __attribute__((ext_vector_type(4))) float floatx4;

__device__ __forceinline__ float gelu_f(float x) {
  return 0.5f * x * (1.0f + erff(x * 0.70710678118654752440f));
}

__device__ __forceinline__ unsigned short f2b(float f) {
  union { float f; unsigned u; } c; c.f = f;
  unsigned r = c.u + 0x7fffu + ((c.u >> 16) & 1u);
  return (unsigned short)(r >> 16);
}

__device__ __forceinline__ float b2f(unsigned short u) {
  union { unsigned u; float f; } c; c.u = ((unsigned)u) << 16; return c.f;
}

// ---------------- weight transpose+convert: W[b][K][N] fp32 -> WT[b][N][K] bf16 ----------------
__global__ __launch_bounds__(256) void transpose_w(const float* __restrict__ W, unsigned short* __restrict__ WT,
                                                   int K, int Ncol, int total) {
  int i = blockIdx.x * 256 + threadIdx.x;
  if (i >= total) return;
  int kn = K * Ncol;
  int b = i / kn, r = i - b * kn;
  int k = r / Ncol, n = r - k * Ncol;
  WT[b * kn + n * K + k] = f2b(W[i]);
}

// ---------------- CSR build ----------------

__global__ __launch_bounds__(256) void hist_kernel(int* __restrict__ cnt, const int* __restrict__ dst, int E) {
  int i = blockIdx.x * 256 + threadIdx.x;
  if (i < E) atomicAdd(&cnt[dst[i]], 1);
}

__global__ __launch_bounds__(256) void scan_a(const int* __restrict__ cnt, int* __restrict__ row_ptr,
                                              int* __restrict__ blockSum, float* __restrict__ dinv, int N) {
  __shared__ int ls[256];
  int t = threadIdx.x;
  int idx = blockIdx.x * 1024 + t * 4;
  int4 v = make_int4(0, 0, 0, 0);
  if (idx + 3 < N) v = *(const int4*)&cnt[idx];
  else {
    if (idx + 0 < N) v.x = cnt[idx + 0];
    if (idx + 1 < N) v.y = cnt[idx + 1];
    if (idx + 2 < N) v.z = cnt[idx + 2];
    if (idx + 3 < N) v.w = cnt[idx + 3];
  }
  if (idx + 0 < N) dinv[idx + 0] = rsqrtf((float)v.x + 1.0f);
  if (idx + 1 < N) dinv[idx + 1] = rsqrtf((float)v.y + 1.0f);
  if (idx + 2 < N) dinv[idx + 2] = rsqrtf((float)v.z + 1.0f);
  if (idx + 3 < N) dinv[idx + 3] = rsqrtf((float)v.w + 1.0f);
  int s = v.x + v.y + v.z + v.w;
  ls[t] = s;
  __syncthreads();
  for (int off = 1; off < 256; off <<= 1) {
    int a = (t >= off) ? ls[t - off] : 0;
    __syncthreads();
    ls[t] += a;
    __syncthreads();
  }
  int p = ls[t] - s;
  if (t == 255) blockSum[blockIdx.x] = ls[255];
  if (idx + 0 < N) row_ptr[idx + 0] = p;  p += v.x;
  if (idx + 1 < N) row_ptr[idx + 1] = p;  p += v.y;
  if (idx + 2 < N) row_ptr[idx + 2] = p;  p += v.z;
  if (idx + 3 < N) row_ptr[idx + 3] = p;
}

__global__ __launch_bounds__(1024) void scan_b(const int* __restrict__ blockSum, int* __restrict__ blockOff,
                                               int nb, int* __restrict__ row_ptr, int N, int E) {
  __shared__ int ls[1024];
  int t = threadIdx.x;
  int s = (t < nb) ? blockSum[t] : 0;
  ls[t] = s;
  __syncthreads();
  for (int off = 1; off < 1024; off <<= 1) {
    int a = (t >= off) ? ls[t - off] : 0;
    __syncthreads();
    ls[t] += a;
    __syncthreads();
  }
  if (t < nb) blockOff[t] = ls[t] - s;
  if (t == 0) row_ptr[N] = E;
}

__global__ __launch_bounds__(256) void scan_c(int* __restrict__ row_ptr, const int* __restrict__ blockOff, int N) {
  int t = threadIdx.x;
  int idx = blockIdx.x * 1024 + t * 4;
  int off = blockOff[blockIdx.x];
  if (off == 0) return;
  if (idx + 3 < N) {
    int4 v = *(const int4*)&row_ptr[idx];
    v.x += off; v.y += off; v.z += off; v.w += off;
    *(int4*)&row_ptr[idx] = v;
  } else {
    if (idx + 0 < N) row_ptr[idx + 0] += off;
    if (idx + 1 < N) row_ptr[idx + 1] += off;
    if (idx + 2 < N) row_ptr[idx + 2] += off;
    if (idx + 3 < N) row_ptr[idx + 3] += off;
  }
}

__global__ __launch_bounds__(256) void build_csr_kernel(const int* __restrict__ src, const int* __restrict__ dst,
                                                        const int* __restrict__ row_ptr, int* __restrict__ cursor,
                                                        const float* __restrict__ dinv,
                                                        int* __restrict__ csr_src, float* __restrict__ csr_norm,
                                                        int E) {
  int i = blockIdx.x * 256 + threadIdx.x;
  if (i < E) {
    int s = src[i], d = dst[i];
    int pos = row_ptr[d] + atomicAdd(&cursor[d], 1);
    csr_src[pos] = s;
    csr_norm[pos] = dinv[s] * dinv[d];
  }
}

// ---------------- small setup kernels ----------------

__global__ __launch_bounds__(256) void count_kernel(float* counts, const int* __restrict__ batch, int N, int G) {
  __shared__ float hist[256];
  int t = threadIdx.x;
  if (t < G) hist[t] = 0.f;
  __syncthreads();
  int i0 = (blockIdx.x * 256 + t) * 16;
  int cur = -1; float run = 0.f;
  for (int j = 0; j < 16; j++) {
    int i = i0 + j;
    if (i < N) {
      int b = batch[i];
      if (b == cur) run += 1.f;
      else { if (cur >= 0) atomicAdd(&hist[cur], run); cur = b; run = 1.f; }
    }
  }
  if (cur >= 0) atomicAdd(&hist[cur], run);
  __syncthreads();
  if (t < G && hist[t] != 0.f) atomicAdd(&counts[t], hist[t]);
}

__global__ __launch_bounds__(256) void vn_init_kernel(float* vn, const float* __restrict__ emb, int n) {
  int i = blockIdx.x * 256 + threadIdx.x;
  if (i < n) vn[i] = emb[i & (H - 1)];
}

// ---------------- fused gather aggregation (bf16 h) ----------------
__global__ __launch_bounds__(256) void gather_agg(const unsigned short* __restrict__ h, const int* __restrict__ csr_src,
                                                  const float* __restrict__ csr_norm, const int* __restrict__ row_ptr,
                                                  const float* __restrict__ dinv, const float* __restrict__ vn,
                                                  const int* __restrict__ batch, const float* __restrict__ bias,
                                                  float* __restrict__ x, int N) {
  int node = blockIdx.x * 4 + (threadIdx.x >> 6);
  if (node >= N) return;
  int lane = threadIdx.x & 63;
  int c = lane * 2;
  float di = dinv[node];
  unsigned hv = *(const unsigned*)&h[(long)node * H + c];
  float ax = b2f((unsigned short)hv) * di * di;
  float ay = b2f((unsigned short)(hv >> 16)) * di * di;
  int beg = row_ptr[node], end = row_ptr[node + 1];
  int e = beg;
  for (; e + 2 <= end; e += 2) {
    int s0 = csr_src[e], s1 = csr_src[e + 1];
    float w0 = csr_norm[e], w1 = csr_norm[e + 1];
    unsigned v0 = *(const unsigned*)&h[(long)s0 * H + c];
    unsigned v1 = *(const unsigned*)&h[(long)s1 * H + c];
    ax += b2f((unsigned short)v0) * w0 + b2f((unsigned short)v1) * w1;
    ay += b2f((unsigned short)(v0 >> 16)) * w0 + b2f((unsigned short)(v1 >> 16)) * w1;
  }
  if (e < end) {
    int s0 = csr_src[e];
    float w0 = csr_norm[e];
    unsigned v0 = *(const unsigned*)&h[(long)s0 * H + c];
    ax += b2f((unsigned short)v0) * w0;
    ay += b2f((unsigned short)(v0 >> 16)) * w0;
  }
  int b = batch[node];
  float2 xo = *(const float2*)&x[(long)node * H + c];
  float2 vv = *(const float2*)&vn[b * H + c];
  float2 bi = *(const float2*)&bias[c];
  float2 r;
  r.x = ax + xo.x + vv.x + bi.x;
  r.y = ay + xo.y + vv.y + bi.y;
  *(float2*)&x[(long)node * H + c] = r;
}

// ---------------- BN stats ----------------

__global__ __launch_bounds__(256) void bn_reduce_kernel(const float* __restrict__ x, float* __restrict__ stats, int N) {
  __shared__ float ls[256], ls2[256];
  int t = threadIdx.x;
  int c = t & (H - 1);
  int r0 = blockIdx.x * 128 + (t >> 7);
  float s = 0.f, s2 = 0.f;
  for (int k = 0; k < 64; k++) {
    int r = r0 + k * 2;
    if (r < N) { float v = x[r * H + c]; s += v; s2 += v * v; }
  }
  ls[t] = s; ls2[t] = s2;
  __syncthreads();
  if (t < 128) {
    atomicAdd(&stats[c], ls[t] + ls[t + 128]);
    atomicAdd(&stats[H + c], ls2[t] + ls2[t + 128]);
  }
}

__global__ __launch_bounds__(128) void bn_finalize_kernel(const float* __restrict__ stats, const float* __restrict__ g,
                                                          const float* __restrict__ b, float* __restrict__ scsh,
                                                          float invN) {
  int c = threadIdx.x;
  float m = stats[c] * invN;
  float v = stats[H + c] * invN - m * m;
  float sc = rsqrtf(v + 1e-5f) * g[c];
  scsh[c] = sc;
  scsh[H + c] = b[c] - m * sc;
}

// ---------------- pooling (run-length over sorted batch) ----------------
__global__ __launch_bounds__(256) void pool_kernel(float* __restrict__ pooled, const float* __restrict__ x,
                                                   const int* __restrict__ batch, int N) {
  int c = threadIdx.x & 127;
  int slab = threadIdx.x >> 7;
  int r0 = blockIdx.x * 128 + slab;
  float acc = 0.f;
  int cur = -1;
  for (int k = 0; k < 64; k++) {
    int r = r0 + k * 2;
    if (r >= N) break;
    int b = batch[r];
    if (b != cur) {
      if (cur >= 0) atomicAdd(&pooled[cur * H + c], acc);
      cur = b; acc = 0.f;
    }
    acc += x[(long)r * H + c];
  }
  if (cur >= 0) atomicAdd(&pooled[cur * H + c], acc);
}

// ---------------- bf16 MFMA GEMM (used for the conv GEMM) ----------------
template <int NT, int ACT, int RES, int HASBIAS, int ASCALE, int AVN, int OUT16>
__global__ __launch_bounds__(256) void gemm_mfma(const float* __restrict__ A,
                                                 const unsigned short* __restrict__ BT,
                                                 const float* __restrict__ bias,
                                                 const float* __restrict__ scshA,
                                                 const float* __restrict__ scshR,
                                                 const float* __restrict__ resid,
                                                 const float* __restrict__ vn,
                                                 const int* __restrict__ batch,
                                                 float* __restrict__ C, unsigned short* __restrict__ C16,
                                                 int M, int K, int Ncol) {
  __shared__ unsigned short As[64 * LDK];
  __shared__ unsigned short Bs[NT * LDK];
  int tid = threadIdx.x;
  int lane = tid & 63, w = tid >> 6;
  int row0 = blockIdx.x * 64;

  floatx4 acc[NT / 16];
#pragma unroll
  for (int t = 0; t < NT / 16; t++) acc[t] = (floatx4)0.f;

  int ar = tid >> 4;
  int ac4 = (tid & 15) * 4;
  int bn = tid >> 3;
  int bk8 = (tid & 7) * 8;

  int mrow = lane & 15;
  int quad = lane >> 4;

  for (int k0 = 0; k0 < K; k0 += 64) {
#pragma unroll
    for (int j = 0; j < 4; j++) {
      int r = j * 16 + ar;
      int gr = row0 + r;
      floatx4 v;
      if (gr < M) v = *(const floatx4*)&A[(long)gr * K + k0 + ac4];
      else v = (floatx4)0.f;
      if (ASCALE) {
        floatx4 sc = *(const floatx4*)&scshA[k0 + ac4];
        floatx4 sh = *(const floatx4*)&scshA[K + k0 + ac4];
        v = v * sc + sh;
      }
      if (AVN) {
        if (gr < M) {
          int b = batch[gr];
          floatx4 vv = *(const floatx4*)&vn[b * H + k0 + ac4];
          v = v + vv;
        }
      }
      unsigned long long p = (unsigned long long)f2b(v.x)
                           | ((unsigned long long)f2b(v.y) << 16)
                           | ((unsigned long long)f2b(v.z) << 32)
                           | ((unsigned long long)f2b(v.w) << 48);
      *(unsigned long long*)&As[r * LDK + ac4] = p;
    }
#pragma unroll
    for (int j = 0; j < NT / 32; j++) {
      int n = j * 32 + bn;
      short8 v = *(const short8*)&BT[(long)n * K + k0 + bk8];
      *(short8*)&Bs[n * LDK + bk8] = v;
    }
    __syncthreads();
#pragma unroll
    for (int kk = 0; kk < 2; kk++) {
      int kb = kk * 32 + quad * 8;
      short8 af = *(const short8*)&As[(w * 16 + mrow) * LDK + kb];
#pragma unroll
      for (int t = 0; t < NT / 16; t++) {
        short8 bf = *(const short8*)&Bs[(t * 16 + mrow) * LDK + kb];
        acc[t] = __builtin_amdgcn_mfma_f32_16x16x32_bf16(af, bf, acc[t], 0, 0, 0);
      }
    }
    __syncthreads();
  }

  int cn = lane & 15;
#pragma unroll
  for (int t = 0; t < NT / 16; t++) {
    int c = t * 16 + cn;
    float b = HASBIAS ? bias[c] : 0.f;
    float rsc = 0.f, rsh = 0.f;
    if (RES == 2) { rsc = scshR[c]; rsh = scshR[H + c]; }
#pragma unroll
    for (int i = 0; i < 4; i++) {
      int r = row0 + w * 16 + quad * 4 + i;
      if (r < M) {
        float v = acc[t][i] + b;
        if (ACT) v = gelu_f(v);
        long off = (long)r * Ncol + c;
        if (OUT16) {
          C16[off] = f2b(v);
        } else {
          if (RES == 1) v += C[off];
          if (RES == 2) v += resid[off] * rsc + rsh;
          C[off] = v;
        }
      }
    }
  }
}

// ---------------- fused 2-layer FFN over 64-row blocks ----------------
// BNRES=1: C = gelu( bf16(gelu(bn(A)@W1+b1)) @ W2 + b2 ) + bn(A) (resid via scsh)
// BNRES=0: C = gelu( bf16(gelu(A@W1+b1)) @ W2 + b2 )               (pre/post-style FFNN)
// A: M x H fp32. W1T: [H2][H] bf16. W2T: [H][H2] bf16. C: M x H fp32.
// LDS overlay: phase1 As(64xLDK)+Bs(H2xLDK)=23040 sh; phase2 Hs(64xLDH)+Bs2(HxLDK)=26112 sh.
template <int BNRES>
__global__ __launch_bounds__(256) void ffn_fused(const float* __restrict__ A,
                                                 const unsigned short* __restrict__ W1T, const float* __restrict__ b1,
                                                 const unsigned short* __restrict__ W2T, const float* __restrict__ b2,
                                                 const float* __restrict__ scsh, const float* __restrict__ resid,
                                                 float* __restrict__ C, int M) {
  __shared__ unsigned short smem[FFN_SMEM];   // 26112 shorts = 52224 B
  unsigned short* As  = smem;                 // phase 1: 64 x LDK
  unsigned short* Bs  = smem + 64 * LDK;      // phase 1: 256 x LDK (ends 23040)
  unsigned short* Hs  = smem;                 // phase 2: 64 x LDH (0..16896)
  unsigned short* Bs2 = smem + 64 * LDH;      // phase 2: 128 x LDK (16896..26112)

  int tid = threadIdx.x;
  int lane = tid & 63, w = tid >> 6;
  int row0 = blockIdx.x * 64;
  int mrow = lane & 15;
  int quad = lane >> 4;
  int cn = lane & 15;

  int ar = tid >> 4;
  int ac4 = (tid & 15) * 4;
  int bn = tid >> 3;
  int bk8 = (tid & 7) * 8;

  // ---- phase 1: hidden = gelu((bn?)(A) @ W1 + b1), 64 x 256
  floatx4 acc[16];
#pragma unroll
  for (int t = 0; t < 16; t++) acc[t] = (floatx4)0.f;

  for (int k0 = 0; k0 < H; k0 += 64) {
#pragma unroll
    for (int j = 0; j < 4; j++) {
      int r = j * 16 + ar;
      int gr = row0 + r;
      floatx4 v;
      if (gr < M) v = *(const floatx4*)&A[(long)gr * H + k0 + ac4];
      else v = (floatx4)0.f;
      if (BNRES) {
        floatx4 sc = *(const floatx4*)&scsh[k0 + ac4];
        floatx4 sh = *(const floatx4*)&scsh[H + k0 + ac4];
        v = v * sc + sh;
      }
      unsigned long long p = (unsigned long long)f2b(v.x)
                           | ((unsigned long long)f2b(v.y) << 16)
                           | ((unsigned long long)f2b(v.z) << 32)
                           | ((unsigned long long)f2b(v.w) << 48);
      *(unsigned long long*)&As[r * LDK + ac4] = p;
    }
#pragma unroll
    for (int j = 0; j < 8; j++) {
      int n = j * 32 + bn;
      short8 v = *(const short8*)&W1T[(long)n * H + k0 + bk8];
      *(short8*)&Bs[n * LDK + bk8] = v;
    }
    __syncthreads();
#pragma unroll
    for (int kk = 0; kk < 2; kk++) {
      int kb = kk * 32 + quad * 8;
      short8 af = *(const short8*)&As[(w * 16 + mrow) * LDK + kb];
#pragma unroll
      for (int t = 0; t < 16; t++) {
        short8 bf = *(const short8*)&Bs[(t * 16 + mrow) * LDK + kb];
        acc[t] = __builtin_amdgcn_mfma_f32_16x16x32_bf16(af, bf, acc[t], 0, 0, 0);
      }
    }
    __syncthreads();
  }

  // ---- spill hidden (gelu+bias, bf16) to Hs
#pragma unroll
  for (int t = 0; t < 16; t++) {
    int c = t * 16 + cn;
    float bb = b1[c];
#pragma unroll
    for (int i = 0; i < 4; i++) {
      int r = w * 16 + quad * 4 + i;
      Hs[r * LDH + c] = f2b(gelu_f(acc[t][i] + bb));
    }
  }

  // ---- phase 2: out = gelu(Hs @ W2 + b2) (+ resid*sc+sh), K = 256
  floatx4 acc2[8];
#pragma unroll
  for (int t = 0; t < 8; t++) acc2[t] = (floatx4)0.f;

  for (int k0 = 0; k0 < H2; k0 += 64) {
#pragma unroll
    for (int j = 0; j < 4; j++) {
      int n = j * 32 + bn;
      short8 v = *(const short8*)&W2T[(long)n * H2 + k0 + bk8];
      *(short8*)&Bs2[n * LDK + bk8] = v;
    }
    __syncthreads();
#pragma unroll
    for (int kk = 0; kk < 2; kk++) {
      int kbh = k0 + kk * 32 + quad * 8;
      int kbs = kk * 32 + quad * 8;
      short8 af = *(const short8*)&Hs[(w * 16 + mrow) * LDH + kbh];
#pragma unroll
      for (int t = 0; t < 8; t++) {
        short8 bf = *(const short8*)&Bs2[(t * 16 + mrow) * LDK + kbs];
        acc2[t] = __builtin_amdgcn_mfma_f32_16x16x32_bf16(af, bf, acc2[t], 0, 0, 0);
      }
    }
    __syncthreads();
  }

#pragma unroll
  for (int t = 0; t < 8; t++) {
    int c = t * 16 + cn;
    float bb = b2[c];
    float rsc = 0.f, rsh = 0.f;
    if (BNRES) { rsc = scsh[c]; rsh = scsh[H + c]; }
#pragma unroll
    for (int i = 0; i < 4; i++) {
      int r = row0 + w * 16 + quad * 4 + i;
      if (r < M) {
        long off = (long)r * H + c;
        float v = gelu_f(acc2[t][i] + bb);
        if (BNRES) v += resid[off] * rsc + rsh;
        C[off] = v;
      }
    }
  }
}

// ---------------- parallel 64-row MLP stages (vn / post) ----------------
template <int BN, int UVN>
__global__ __launch_bounds__(256) void mlp64_l1(const float* __restrict__ vn, const float* __restrict__ pooled,
                                                const float* __restrict__ counts,
                                                const float* __restrict__ W1, const float* __restrict__ b1,
                                                const float* __restrict__ g1, const float* __restrict__ be1,
                                                float* __restrict__ h1) {
  __shared__ float u[64 * H];
  __shared__ float red[8 * 64];
  int t = threadIdx.x;
  for (int idx = t; idx < 64 * H; idx += 256) {
    float v = pooled[idx];
    if (UVN) v = vn[idx] + v / fmaxf(counts[idx >> 7], 1.0f);
    u[idx] = v;
  }
  __syncthreads();
  int tc = t & 63, tg = t >> 6;
  int c = blockIdx.x * 64 + tc;
  float acc[16];
  float bj = b1[c];
#pragma unroll
  for (int g = 0; g < 16; g++) acc[g] = bj;
  for (int k0 = 0; k0 < H; k0 += 4) {
    float w0 = W1[(k0 + 0) * H2 + c];
    float w1 = W1[(k0 + 1) * H2 + c];
    float w2 = W1[(k0 + 2) * H2 + c];
    float w3 = W1[(k0 + 3) * H2 + c];
#pragma unroll
    for (int g = 0; g < 16; g++) {
      float4 v = *(const float4*)&u[(tg * 16 + g) * H + k0];
      acc[g] += v.x * w0 + v.y * w1 + v.z * w2 + v.w * w3;
    }
  }
  float sc = 1.f, sh = 0.f;
  if (BN) {
    float s = 0.f, s2 = 0.f;
#pragma unroll
    for (int g = 0; g < 16; g++) { s += acc[g]; s2 += acc[g] * acc[g]; }
    red[tg * 64 + tc] = s;
    red[256 + tg * 64 + tc] = s2;
    __syncthreads();
    float st = red[tc] + red[64 + tc] + red[128 + tc] + red[192 + tc];
    float st2 = red[256 + tc] + red[320 + tc] + red[384 + tc] + red[448 + tc];
    float m = st * (1.f / 64.f);
    float var = st2 * (1.f / 64.f) - m * m;
    sc = rsqrtf(var + 1e-5f) * g1[c];
    sh = be1[c] - m * sc;
  }
#pragma unroll
  for (int g = 0; g < 16; g++) h1[(tg * 16 + g) * H2 + c] = gelu_f(acc[g] * sc + sh);
}

template <int BN>
__global__ __launch_bounds__(256) void mlp64_l2(const float* __restrict__ h1,
                                                const float* __restrict__ W2, const float* __restrict__ b2,
                                                const float* __restrict__ g2, const float* __restrict__ be2,
                                                float* __restrict__ outp) {
  __shared__ float red[8 * 64];
  int t = threadIdx.x;
  int tc = t & 63, tg = t >> 6;
  int c = blockIdx.x * 64 + tc;
  float acc[16];
  float bj = b2[c];
#pragma unroll
  for (int g = 0; g < 16; g++) acc[g] = bj;
  for (int k0 = 0; k0 < H2; k0 += 4) {
    float w0 = W2[(k0 + 0) * H + c];
    float w1 = W2[(k0 + 1) * H + c];
    float w2 = W2[(k0 + 2) * H + c];
    float w3 = W2[(k0 + 3) * H + c];
#pragma unroll
    for (int g = 0; g < 16; g++) {
      float4 v = *(const float4*)&h1[(tg * 16 + g) * H2 + k0];
      acc[g] += v.x * w0 + v.y * w1 + v.z * w2 + v.w * w3;
    }
  }
  float sc = 1.f, sh = 0.f;
  if (BN) {
    float s = 0.f, s2 = 0.f;
#pragma unroll
    for (int g = 0; g < 16; g++) { s += acc[g]; s2 += acc[g] * acc[g]; }
    red[tg * 64 + tc] = s;
    red[256 + tg * 64 + tc] = s2;
    __syncthreads();
    float st = red[tc] + red[64 + tc] + red[128 + tc] + red[192 + tc];
    float st2 = red[256 + tc] + red[320 + tc] + red[384 + tc] + red[448 + tc];
    float m = st * (1.f / 64.f);
    float var = st2 * (1.f / 64.f) - m * m;
    sc = rsqrtf(var + 1e-5f) * g2[c];
    sh = be2[c] - m * sc;
  }
#pragma unroll
  for (int g = 0; g < 16; g++) outp[(tg * 16 + g) * H + c] = gelu_f(acc[g] * sc + sh);
}

// ---------------- host launch ----------------

extern "C" void kernel_launch(void* const* d_in, const int* in_sizes, int n_in,
                              void* d_out, int out_size, void* d_ws, size_t ws_size,
                              hipStream_t stream) {
  const float* x_in   = (const float*)d_in[0];
  const int*   edge   = (const int*)d_in[1];
  const int*   batch  = (const int*)d_in[2];
  const float* pre_W1 = (const float*)d_in[3];
  const float* pre_b1 = (const float*)d_in[4];
  const float* pre_W2 = (const float*)d_in[5];
  const float* pre_b2 = (const float*)d_in[6];
  const float* conv_W = (const float*)d_in[7];
  const float* conv_b = (const float*)d_in[8];
  const float* bn_g   = (const float*)d_in[9];
  const float* bn_b   = (const float*)d_in[10];
  const float* ffn_W1 = (const float*)d_in[11];
  const float* ffn_b1 = (const float*)d_in[12];
  const float* ffn_W2 = (const float*)d_in[13];
  const float* ffn_b2 = (const float*)d_in[14];
  const float* vn_W1  = (const float*)d_in[15];
  const float* vn_b1  = (const float*)d_in[16];
  const float* vn_g1  = (const float*)d_in[17];
  const float* vn_be1 = (const float*)d_in[18];
  const float* vn_W2  = (const float*)d_in[19];
  const float* vn_b2  = (const float*)d_in[20];
  const float* vn_g2  = (const float*)d_in[21];
  const float* vn_be2 = (const float*)d_in[22];
  const float* vn_emb = (const float*)d_in[23];
  const float* post_W1= (const float*)d_in[24];
  const float* post_b1= (const float*)d_in[25];
  const float* post_W2= (const float*)d_in[26];
  const float* post_b2= (const float*)d_in[27];
  float* out = (float*)d_out;

  const int N    = in_sizes[2];
  const int E    = in_sizes[1] / 2;
  const int G    = out_size / H;
  const int HOPS = in_sizes[7] / (H * H);
  const int NH   = N * H;

  // workspace layout
  float* w = (float*)d_ws;
  float* buf_x  = w;  w += NH;
  float* buf_t  = w;  w += N * H2;   // holds bf16 conv output h16 (first NH shorts)
  unsigned short* buf_h16 = (unsigned short*)buf_t;
  float* dinv   = w;  w += N;
  float* counts = w;  w += G;
  float* stats  = w;  w += 2 * H;
  float* scsh   = w;  w += 2 * H;
  float* pooled = w;  w += G * H;
  float* vn     = w;  w += G * H;
  float* mlp_h1 = w;  w += G * H2;
  float* csr_norm = w; w += E;
  int* iw = (int*)w;
  int* cnt      = iw;  iw += N;
  int* row_ptr  = iw;  iw += N + 1;
  int* cursor   = iw;  iw += N;
  int* csr_src  = iw;  iw += E;
  int* blockSum = iw;  iw += 1024;
  int* blockOff = iw;  iw += 1024;
  unsigned short* wt = (unsigned short*)iw;
  unsigned short* preW1T = wt;  wt += H * H2;
  unsigned short* preW2T = wt;  wt += H2 * H;
  unsigned short* convT  = wt;  wt += HOPS * H * H;
  unsigned short* ffn1T  = wt;  wt += HOPS * H * H2;
  unsigned short* ffn2T  = wt;  wt += HOPS * H2 * H;

  const int* src = edge;
  const int* dst = edge + E;

  int gE  = (E + 255) / 256;
  int gM  = (N + 63) / 64;
  int nb  = (N + 1023) / 1024;

  // weight transposes
  transpose_w<<<(H * H2 + 255) / 256, 256, 0, stream>>>(pre_W1, preW1T, H, H2, H * H2);
  transpose_w<<<(H2 * H + 255) / 256, 256, 0, stream>>>(pre_W2, preW2T, H2, H, H2 * H);
  transpose_w<<<(HOPS * H * H + 255) / 256, 256, 0, stream>>>(conv_W, convT, H, H, HOPS * H * H);
  transpose_w<<<(HOPS * H * H2 + 255) / 256, 256, 0, stream>>>(ffn_W1, ffn1T, H, H2, HOPS * H * H2);
  transpose_w<<<(HOPS * H2 * H + 255) / 256, 256, 0, stream>>>(ffn_W2, ffn2T, H2, H, HOPS * H2 * H);

  // CSR build + dinv
  hipMemsetAsync(cnt, 0, N * sizeof(int), stream);
  hist_kernel<<<gE, 256, 0, stream>>>(cnt, dst, E);
  scan_a<<<nb, 256, 0, stream>>>(cnt, row_ptr, blockSum, dinv, N);
  scan_b<<<1, 1024, 0, stream>>>(blockSum, blockOff, nb, row_ptr, N, E);
  scan_c<<<nb, 256, 0, stream>>>(row_ptr, blockOff, N);
  hipMemsetAsync(cursor, 0, N * sizeof(int), stream);
  build_csr_kernel<<<gE, 256, 0, stream>>>(src, dst, row_ptr, cursor, dinv, csr_src, csr_norm, E);

  // graph counts, vn init
  hipMemsetAsync(counts, 0, G * sizeof(float), stream);
  count_kernel<<<(N + 256 * 16 - 1) / (256 * 16), 256, 0, stream>>>(counts, batch, N, G);
  vn_init_kernel<<<(G * H + 255) / 256, 256, 0, stream>>>(vn, vn_emb, G * H);

  // pre-FFNN (fused pair)
  ffn_fused<0><<<gM, 256, 0, stream>>>(x_in, preW1T, pre_b1, preW2T, pre_b2, nullptr, nullptr, buf_x, N);

  for (int i = 0; i < HOPS; i++) {
    // GCN: h16 = bf16( (x + vn[batch]) @ W )
    gemm_mfma<128, 0, 0, 0, 0, 1, 1><<<gM, 256, 0, stream>>>(buf_x, convT + i * H * H, nullptr, nullptr, nullptr, nullptr, vn, batch, nullptr, buf_h16, N, H, H);
    // x = x + vn[batch] + bias + selfloop + gathered edges
    gather_agg<<<(N + 3) / 4, 256, 0, stream>>>(buf_h16, csr_src, csr_norm, row_ptr, dinv, vn, batch, conv_b + i * H, buf_x, N);
    // BN stats (apply fused into the fused-FFN)
    hipMemsetAsync(stats, 0, 2 * H * sizeof(float), stream);
    bn_reduce_kernel<<<(N + 127) / 128, 256, 0, stream>>>(buf_x, stats, N);
    bn_finalize_kernel<<<1, 128, 0, stream>>>(stats, bn_g + i * H, bn_b + i * H, scsh, 1.0f / (float)N);
    // fused FFN: x = gelu(gelu(bn(x)@W1+b1)@W2+b2) + bn(x)
    ffn_fused<1><<<gM, 256, 0, stream>>>(buf_x, ffn1T + i * H * H2, ffn_b1 + i * H2,
                                         ffn2T + i * H2 * H, ffn_b2 + i * H, scsh, buf_x, buf_x, N);
    // virtual node update
    if (i < HOPS - 1) {
      hipMemsetAsync(pooled, 0, G * H * sizeof(float), stream);
      pool_kernel<<<(N + 127) / 128, 256, 0, stream>>>(pooled, buf_x, batch, N);
      mlp64_l1<1, 1><<<H2 / 64, 256, 0, stream>>>(vn, pooled, counts,
                                                  vn_W1 + i * H * H2, vn_b1 + i * H2, vn_g1 + i * H2, vn_be1 + i * H2,
                                                  mlp_h1);
      mlp64_l2<1><<<H / 64, 256, 0, stream>>>(mlp_h1, vn_W2 + i * H2 * H, vn_b2 + i * H, vn_g2 + i * H, vn_be2 + i * H, vn);
    }
  }

  // final global_add_pool + post-FFNN
  hipMemsetAsync(pooled, 0, G * H * sizeof(float), stream);
  pool_kernel<<<(N + 127) / 128, 256, 0, stream>>>(pooled, buf_x, batch, N);
  mlp64_l1<0, 0><<<H2 / 64, 256, 0, stream>>>(nullptr, pooled, nullptr, post_W1, post_b1, nullptr, nullptr, mlp_h1);
  mlp64_l2<0><<<H / 64, 256, 0, stream>>>(mlp_h1, post_W2, post_b2, nullptr, nullptr, out);
}